// Round 3
// baseline (587.026 us; speedup 1.0000x reference)
//
#include <hip/hip_runtime.h>
#include <hip/hip_bf16.h>

#define NROWS 8192
#define NITER 10

typedef __attribute__((ext_vector_type(8))) short bf16x8;
typedef __attribute__((ext_vector_type(8))) unsigned short u16x8;
typedef __attribute__((ext_vector_type(16))) float f32x16;

__device__ __forceinline__ float bf2f(unsigned short u) {
  union { float f; unsigned int i; } c; c.i = ((unsigned int)u) << 16; return c.f;
}
__device__ __forceinline__ unsigned short f2bf(float f) {
  unsigned int x = __float_as_uint(f);
  unsigned int r = (x + 0x7FFFu + ((x >> 16) & 1u)) >> 16;
  return (unsigned short)r;
}

// C[M,NN] = A[M,K] * B[NN,K]^T   (fp32, 64x64 tile, 4x4 per thread)
__global__ __launch_bounds__(256) void gemm_bt(const float* __restrict__ A,
                                               const float* __restrict__ B,
                                               float* __restrict__ C,
                                               int M, int NN, int K) {
  __shared__ float As[16][68];
  __shared__ float Bs[16][68];
  const int t = threadIdx.x;
  const int m0 = blockIdx.x * 64, n0 = blockIdx.y * 64;
  const int lr = t >> 2, lc = t & 3;
  const int ty = t >> 4, tx = t & 15;
  float acc[4][4];
#pragma unroll
  for (int i = 0; i < 4; ++i)
#pragma unroll
    for (int j = 0; j < 4; ++j) acc[i][j] = 0.f;
  for (int kt = 0; kt < K; kt += 16) {
    float4 av = *(const float4*)(A + (size_t)(m0 + lr) * K + kt + lc * 4);
    float4 bv = *(const float4*)(B + (size_t)(n0 + lr) * K + kt + lc * 4);
    __syncthreads();
    As[lc * 4 + 0][lr] = av.x; As[lc * 4 + 1][lr] = av.y;
    As[lc * 4 + 2][lr] = av.z; As[lc * 4 + 3][lr] = av.w;
    Bs[lc * 4 + 0][lr] = bv.x; Bs[lc * 4 + 1][lr] = bv.y;
    Bs[lc * 4 + 2][lr] = bv.z; Bs[lc * 4 + 3][lr] = bv.w;
    __syncthreads();
#pragma unroll
    for (int k = 0; k < 16; ++k) {
      float4 a4 = *(const float4*)&As[k][ty * 4];
      float4 b4 = *(const float4*)&Bs[k][tx * 4];
      float a[4] = {a4.x, a4.y, a4.z, a4.w};
      float b[4] = {b4.x, b4.y, b4.z, b4.w};
#pragma unroll
      for (int i = 0; i < 4; ++i)
#pragma unroll
        for (int j = 0; j < 4; ++j) acc[i][j] += a[i] * b[j];
    }
  }
#pragma unroll
  for (int i = 0; i < 4; ++i) {
    float4 o = make_float4(acc[i][0], acc[i][1], acc[i][2], acc[i][3]);
    *(float4*)(C + (size_t)(m0 + ty * 4 + i) * NN + n0 + tx * 4) = o;
  }
}

// per-column partial sums (deterministic two-stage BN stats)
__global__ __launch_bounds__(256) void colstats(const float* __restrict__ in, int C,
                                                float* __restrict__ pS,
                                                float* __restrict__ pSS) {
  const int t = threadIdx.x;
  const int col = blockIdx.x * 64 + (t & 63);
  const int rp = t >> 6;
  const int r0 = blockIdx.y * 128;
  float s = 0.f, ss = 0.f;
  for (int r = rp; r < 128; r += 4) {
    float v = in[(size_t)(r0 + r) * C + col];
    s += v; ss += v * v;
  }
  __shared__ float lS[4][64], lQ[4][64];
  lS[rp][t & 63] = s; lQ[rp][t & 63] = ss;
  __syncthreads();
  if (t < 64) {
    float ts = lS[0][t] + lS[1][t] + lS[2][t] + lS[3][t];
    float tq = lQ[0][t] + lQ[1][t] + lQ[2][t] + lQ[3][t];
    pS[(size_t)blockIdx.y * C + blockIdx.x * 64 + t] = ts;
    pSS[(size_t)blockIdx.y * C + blockIdx.x * 64 + t] = tq;
  }
}

__global__ void bn_finalize(const float* __restrict__ pS, const float* __restrict__ pSS,
                            const float* __restrict__ g, const float* __restrict__ be,
                            float2* __restrict__ ab, int C) {
  int c = blockIdx.x * 256 + threadIdx.x;
  if (c >= C) return;
  float s = 0.f, q = 0.f;
  for (int r = 0; r < 64; ++r) { s += pS[r * C + c]; q += pSS[r * C + c]; }
  const float invM = 1.f / 8192.f;
  float mu = s * invM;
  float var = q * invM - mu * mu;
  float rstd = rsqrtf(var + 1e-5f);
  float a = g[c] * rstd;
  ab[c] = make_float2(a, be[c] - mu * a);
}

// in-place: h = leaky_relu(a*h + b), per column
__global__ __launch_bounds__(256) void bn_act(float* __restrict__ h,
                                              const float2* __restrict__ ab,
                                              int Cmask) {
  size_t idx = (size_t)blockIdx.x * 256 + threadIdx.x;
  float4 v = ((const float4*)h)[idx];
  int cb = (int)((idx * 4) & (size_t)Cmask);
  float2 a0 = ab[cb], a1 = ab[cb + 1], a2 = ab[cb + 2], a3 = ab[cb + 3];
  float r0 = a0.x * v.x + a0.y; r0 = r0 >= 0.f ? r0 : 0.01f * r0;
  float r1 = a1.x * v.y + a1.y; r1 = r1 >= 0.f ? r1 : 0.01f * r1;
  float r2 = a2.x * v.z + a2.y; r2 = r2 >= 0.f ? r2 : 0.01f * r2;
  float r3 = a3.x * v.w + a3.y; r3 = r3 >= 0.f ? r3 : 0.01f * r3;
  ((float4*)h)[idx] = make_float4(r0, r1, r2, r3);
}

// per row: fn, unary logit, coef0; write row-normalized feats as bf16
__global__ __launch_bounds__(256) void rowfn(const float* __restrict__ feats,
                                             const float* __restrict__ fcw,
                                             const float* __restrict__ fcb,
                                             unsigned short* __restrict__ fnorm,
                                             float* __restrict__ unary,
                                             float* __restrict__ coef0) {
  const int lane = threadIdx.x & 63;
  const int row = blockIdx.x * 4 + (threadIdx.x >> 6);
  const float* fr = feats + (size_t)row * 256;
  float4 v = *(const float4*)(fr + lane * 4);
  float4 w = *(const float4*)(fcw + lane * 4);
  float ssq = v.x * v.x + v.y * v.y + v.z * v.z + v.w * v.w;
  float dot = v.x * w.x + v.y * w.y + v.z * w.z + v.w * w.w;
#pragma unroll
  for (int o = 32; o; o >>= 1) { ssq += __shfl_xor(ssq, o); dot += __shfl_xor(dot, o); }
  float rfn = rsqrtf(ssq);
  *(ushort4*)(fnorm + (size_t)row * 256 + lane * 4) =
      make_ushort4(f2bf(v.x * rfn), f2bf(v.y * rfn), f2bf(v.z * rfn), f2bf(v.w * rfn));
  if (lane == 0) {
    float lg = dot + fcb[0];
    unary[row] = lg;
    coef0[row] = 1.f - 2.f / (1.f + __expf(-lg));
  }
}

// PP[i,j] = (fnorm_i . fnorm_j) * 0.5*(W[i,j]+W[j,i])  stored bf16
// Symmetric: only bi<=bj tile pairs; MFMA operands loaded DIRECTLY from
// global fnorm (L2-resident, fragment = 8 contiguous bf16/lane) - no LDS,
// no barriers in the K-loop.
__global__ __launch_bounds__(256, 4) void ppbuild_sym(const unsigned short* __restrict__ fnorm,
                                                      const float* __restrict__ W,
                                                      unsigned short* __restrict__ PP) {
  const int bi = blockIdx.x, bj = blockIdx.y;
  if (bj < bi) return;
  const int i0 = bi * 64, j0 = bj * 64;
  __shared__ __align__(16) unsigned char shm[18944];  // union: Wt | OutD+OutT
  float (*Wt)[65] = (float(*)[65])shm;                // 64x65 fp32 = 16640 B
  unsigned short* OutD = (unsigned short*)shm;        // 64x74 ushort = 9472 B
  unsigned short* OutT = (unsigned short*)(shm + 9472);
  const int t = threadIdx.x;

  // stage transposed W block: Wt[j][i] = W[(j0+j)*N + i0+i]  (coalesced)
  {
    const int j = t >> 2, cb = (t & 3) * 16;
    const float* src = W + (size_t)(j0 + j) * NROWS + i0 + cb;
#pragma unroll
    for (int q = 0; q < 4; ++q) {
      float4 v = *(const float4*)(src + q * 4);
      Wt[j][cb + q * 4 + 0] = v.x; Wt[j][cb + q * 4 + 1] = v.y;
      Wt[j][cb + q * 4 + 2] = v.z; Wt[j][cb + q * 4 + 3] = v.w;
    }
  }

  const int lane = t & 63;
  const int wv = t >> 6;
  const int wi = wv >> 1, wj = wv & 1;
  const int khalf = lane >> 5;

  // MFMA K-loop: fragments straight from global (row = lane&31, k = khalf*8+e)
  const unsigned short* pa = fnorm + (size_t)(i0 + wi * 32 + (lane & 31)) * 256 + khalf * 8;
  const unsigned short* pbr = fnorm + (size_t)(j0 + wj * 32 + (lane & 31)) * 256 + khalf * 8;
  f32x16 acc;
#pragma unroll
  for (int r = 0; r < 16; ++r) acc[r] = 0.f;
#pragma unroll
  for (int s = 0; s < 16; ++s) {
    bf16x8 a = *(const bf16x8*)(pa + s * 16);
    bf16x8 b = *(const bf16x8*)(pbr + s * 16);
    acc = __builtin_amdgcn_mfma_f32_32x32x16_bf16(a, b, acc, 0, 0, 0);
  }

  __syncthreads();  // Wt writes visible before epilogue reads
  unsigned short pb[16];
#pragma unroll
  for (int r = 0; r < 16; ++r) {
    int rowl = (r & 3) + 8 * (r >> 2) + 4 * khalf;
    int coll = lane & 31;
    int il = wi * 32 + rowl, jl = wj * 32 + coll;
    float wd = W[(size_t)(i0 + il) * NROWS + (j0 + jl)];
    float ws = 0.5f * (wd + Wt[jl][il]);
    pb[r] = f2bf(acc[r] * ws);
  }
  __syncthreads();  // done reading Wt; reuse LDS for output bounce
#pragma unroll
  for (int r = 0; r < 16; ++r) {
    int rowl = (r & 3) + 8 * (r >> 2) + 4 * khalf;
    int coll = lane & 31;
    int il = wi * 32 + rowl, jl = wj * 32 + coll;
    OutD[il * 74 + jl] = pb[r];
    OutT[jl * 74 + il] = pb[r];
  }
  __syncthreads();
  const int row = t >> 3;      // 0..31
  const int seg = t & 7;       // 0..7
#pragma unroll
  for (int q = 0; q < 2; ++q) {
    int rr = row + q * 32;
    const unsigned int* pd = (const unsigned int*)(OutD + rr * 74 + seg * 8);
    const unsigned int* pt = (const unsigned int*)(OutT + rr * 74 + seg * 8);
    union { u16x8 v; unsigned int u[4]; } dd, tt;
#pragma unroll
    for (int k = 0; k < 4; ++k) { dd.u[k] = pd[k]; tt.u[k] = pt[k]; }
    *(u16x8*)(PP + (size_t)(i0 + rr) * NROWS + j0 + seg * 8) = dd.v;
    *(u16x8*)(PP + (size_t)(j0 + rr) * NROWS + i0 + seg * 8) = tt.v;
  }
}

// one row of E = PP @ coef; lg = unary + E; coef_out = 1-2*sigmoid(lg)
__global__ __launch_bounds__(256) void ppmv(const unsigned short* __restrict__ PP,
                                            const float* __restrict__ coef_in,
                                            const float* __restrict__ unary,
                                            float* __restrict__ coef_out,
                                            float* __restrict__ lg_out) {
  const int i = blockIdx.x;
  const unsigned short* row = PP + (size_t)i * NROWS;
  float acc = 0.f;
#pragma unroll
  for (int cc = 0; cc < 4; ++cc) {
    int j0 = (cc * 256 + threadIdx.x) * 8;
    u16x8 p = *(const u16x8*)(row + j0);
    float4 c0 = *(const float4*)(coef_in + j0);
    float4 c1 = *(const float4*)(coef_in + j0 + 4);
    acc += bf2f(p[0]) * c0.x + bf2f(p[1]) * c0.y + bf2f(p[2]) * c0.z + bf2f(p[3]) * c0.w;
    acc += bf2f(p[4]) * c1.x + bf2f(p[5]) * c1.y + bf2f(p[6]) * c1.z + bf2f(p[7]) * c1.w;
  }
#pragma unroll
  for (int o = 32; o; o >>= 1) acc += __shfl_xor(acc, o);
  __shared__ float red[4];
  if ((threadIdx.x & 63) == 0) red[threadIdx.x >> 6] = acc;
  __syncthreads();
  if (threadIdx.x == 0) {
    float tot = red[0] + red[1] + red[2] + red[3];
    float lg = unary[i] + tot;
    coef_out[i] = 1.f - 2.f / (1.f + __expf(-lg));
    if (lg_out) lg_out[i] = lg;
  }
}

extern "C" void kernel_launch(void* const* d_in, const int* in_sizes, int n_in,
                              void* d_out, int out_size, void* d_ws, size_t ws_size,
                              hipStream_t stream) {
  const float* x   = (const float*)d_in[0];
  const float* W   = (const float*)d_in[1];
  const float* W1  = (const float*)d_in[2];
  const float* g1  = (const float*)d_in[4];
  const float* be1 = (const float*)d_in[5];
  const float* W2  = (const float*)d_in[6];
  const float* g2  = (const float*)d_in[8];
  const float* be2 = (const float*)d_in[9];
  const float* fcw = (const float*)d_in[10];
  const float* fcb = (const float*)d_in[11];
  float* out = (float*)d_out;

  char* ws = (char*)d_ws;
  float* h      = (float*)(ws + 0);              // 8192*512*4  = 16 MB
  float* feats  = (float*)(ws + 16777216);       // 8192*256*4  = 8 MB
  float* p1s    = (float*)(ws + 25165824);       // 64*512*4
  float* p1q    = (float*)(ws + 25296896);       // 64*512*4
  float* p2s    = (float*)(ws + 25427968);       // 64*256*4
  float* p2q    = (float*)(ws + 25493504);       // 64*256*4
  float2* ab1   = (float2*)(ws + 25559040);      // 512*8
  float2* ab2   = (float2*)(ws + 25563136);      // 256*8
  unsigned short* fnorm = (unsigned short*)(ws + 25565184);  // 8192*256*2 = 4 MB
  float* unary  = (float*)(ws + 29759488);       // 8192*4
  float* coefA  = (float*)(ws + 29792256);       // 8192*4
  float* coefB  = (float*)(ws + 29825024);       // 8192*4
  unsigned short* PP = (unsigned short*)(ws + 29857792);     // 8192*8192*2 = 128 MB
  if (ws_size < (size_t)29857792 + (size_t)NROWS * NROWS * 2) return;

  // layer 1: h = x @ W1^T ; BN ; leaky
  gemm_bt<<<dim3(128, 8), 256, 0, stream>>>(x, W1, h, 8192, 512, 128);
  colstats<<<dim3(8, 64), 256, 0, stream>>>(h, 512, p1s, p1q);
  bn_finalize<<<2, 256, 0, stream>>>(p1s, p1q, g1, be1, ab1, 512);
  bn_act<<<4096, 256, 0, stream>>>(h, ab1, 511);
  // layer 2: feats = h @ W2^T ; BN ; leaky
  gemm_bt<<<dim3(128, 4), 256, 0, stream>>>(h, W2, feats, 8192, 256, 512);
  colstats<<<dim3(4, 64), 256, 0, stream>>>(feats, 256, p2s, p2q);
  bn_finalize<<<1, 256, 0, stream>>>(p2s, p2q, g2, be2, ab2, 256);
  bn_act<<<2048, 256, 0, stream>>>(feats, ab2, 255);
  // row norms + unary logits + coef0
  rowfn<<<2048, 256, 0, stream>>>(feats, fcw, fcb, fnorm, unary, coefA);
  // PP = sim * W_sym  (bf16), symmetric tile-pair build
  ppbuild_sym<<<dim3(128, 128), 256, 0, stream>>>(fnorm, W, PP);
  // 10 sequential matvec iterations
  float* cur = coefA; float* nxt = coefB;
  for (int it = 0; it < NITER; ++it) {
    ppmv<<<8192, 256, 0, stream>>>(PP, cur, unary, nxt, it == NITER - 1 ? out : nullptr);
    float* tmp = cur; cur = nxt; nxt = tmp;
  }
}

// Round 4
// 541.528 us; speedup vs baseline: 1.0840x; 1.0840x over previous
//
#include <hip/hip_runtime.h>
#include <hip/hip_bf16.h>

#define NROWS 8192
#define NITER 10

typedef __attribute__((ext_vector_type(8))) short bf16x8;
typedef __attribute__((ext_vector_type(8))) unsigned short u16x8;
typedef __attribute__((ext_vector_type(16))) float f32x16;

__device__ __forceinline__ float bf2f(unsigned short u) {
  union { float f; unsigned int i; } c; c.i = ((unsigned int)u) << 16; return c.f;
}
__device__ __forceinline__ unsigned short f2bf(float f) {
  unsigned int x = __float_as_uint(f);
  unsigned int r = (x + 0x7FFFu + ((x >> 16) & 1u)) >> 16;
  return (unsigned short)r;
}

// C[M,NN] = A[M,K] * B[NN,K]^T   (fp32, 64x64 tile, 4x4 per thread)
__global__ __launch_bounds__(256) void gemm_bt(const float* __restrict__ A,
                                               const float* __restrict__ B,
                                               float* __restrict__ C,
                                               int M, int NN, int K) {
  __shared__ float As[16][68];
  __shared__ float Bs[16][68];
  const int t = threadIdx.x;
  const int m0 = blockIdx.x * 64, n0 = blockIdx.y * 64;
  const int lr = t >> 2, lc = t & 3;
  const int ty = t >> 4, tx = t & 15;
  float acc[4][4];
#pragma unroll
  for (int i = 0; i < 4; ++i)
#pragma unroll
    for (int j = 0; j < 4; ++j) acc[i][j] = 0.f;
  for (int kt = 0; kt < K; kt += 16) {
    float4 av = *(const float4*)(A + (size_t)(m0 + lr) * K + kt + lc * 4);
    float4 bv = *(const float4*)(B + (size_t)(n0 + lr) * K + kt + lc * 4);
    __syncthreads();
    As[lc * 4 + 0][lr] = av.x; As[lc * 4 + 1][lr] = av.y;
    As[lc * 4 + 2][lr] = av.z; As[lc * 4 + 3][lr] = av.w;
    Bs[lc * 4 + 0][lr] = bv.x; Bs[lc * 4 + 1][lr] = bv.y;
    Bs[lc * 4 + 2][lr] = bv.z; Bs[lc * 4 + 3][lr] = bv.w;
    __syncthreads();
#pragma unroll
    for (int k = 0; k < 16; ++k) {
      float4 a4 = *(const float4*)&As[k][ty * 4];
      float4 b4 = *(const float4*)&Bs[k][tx * 4];
      float a[4] = {a4.x, a4.y, a4.z, a4.w};
      float b[4] = {b4.x, b4.y, b4.z, b4.w};
#pragma unroll
      for (int i = 0; i < 4; ++i)
#pragma unroll
        for (int j = 0; j < 4; ++j) acc[i][j] += a[i] * b[j];
    }
  }
#pragma unroll
  for (int i = 0; i < 4; ++i) {
    float4 o = make_float4(acc[i][0], acc[i][1], acc[i][2], acc[i][3]);
    *(float4*)(C + (size_t)(m0 + ty * 4 + i) * NN + n0 + tx * 4) = o;
  }
}

// per-column partial sums (deterministic two-stage BN stats)
__global__ __launch_bounds__(256) void colstats(const float* __restrict__ in, int C,
                                                float* __restrict__ pS,
                                                float* __restrict__ pSS) {
  const int t = threadIdx.x;
  const int col = blockIdx.x * 64 + (t & 63);
  const int rp = t >> 6;
  const int r0 = blockIdx.y * 128;
  float s = 0.f, ss = 0.f;
  for (int r = rp; r < 128; r += 4) {
    float v = in[(size_t)(r0 + r) * C + col];
    s += v; ss += v * v;
  }
  __shared__ float lS[4][64], lQ[4][64];
  lS[rp][t & 63] = s; lQ[rp][t & 63] = ss;
  __syncthreads();
  if (t < 64) {
    float ts = lS[0][t] + lS[1][t] + lS[2][t] + lS[3][t];
    float tq = lQ[0][t] + lQ[1][t] + lQ[2][t] + lQ[3][t];
    pS[(size_t)blockIdx.y * C + blockIdx.x * 64 + t] = ts;
    pSS[(size_t)blockIdx.y * C + blockIdx.x * 64 + t] = tq;
  }
}

__global__ void bn_finalize(const float* __restrict__ pS, const float* __restrict__ pSS,
                            const float* __restrict__ g, const float* __restrict__ be,
                            float2* __restrict__ ab, int C) {
  int c = blockIdx.x * 256 + threadIdx.x;
  if (c >= C) return;
  float s = 0.f, q = 0.f;
  for (int r = 0; r < 64; ++r) { s += pS[r * C + c]; q += pSS[r * C + c]; }
  const float invM = 1.f / 8192.f;
  float mu = s * invM;
  float var = q * invM - mu * mu;
  float rstd = rsqrtf(var + 1e-5f);
  float a = g[c] * rstd;
  ab[c] = make_float2(a, be[c] - mu * a);
}

// in-place: h = leaky_relu(a*h + b), per column
__global__ __launch_bounds__(256) void bn_act(float* __restrict__ h,
                                              const float2* __restrict__ ab,
                                              int Cmask) {
  size_t idx = (size_t)blockIdx.x * 256 + threadIdx.x;
  float4 v = ((const float4*)h)[idx];
  int cb = (int)((idx * 4) & (size_t)Cmask);
  float2 a0 = ab[cb], a1 = ab[cb + 1], a2 = ab[cb + 2], a3 = ab[cb + 3];
  float r0 = a0.x * v.x + a0.y; r0 = r0 >= 0.f ? r0 : 0.01f * r0;
  float r1 = a1.x * v.y + a1.y; r1 = r1 >= 0.f ? r1 : 0.01f * r1;
  float r2 = a2.x * v.z + a2.y; r2 = r2 >= 0.f ? r2 : 0.01f * r2;
  float r3 = a3.x * v.w + a3.y; r3 = r3 >= 0.f ? r3 : 0.01f * r3;
  ((float4*)h)[idx] = make_float4(r0, r1, r2, r3);
}

// per row: fn, unary logit, coef0; write row-normalized feats as bf16
__global__ __launch_bounds__(256) void rowfn(const float* __restrict__ feats,
                                             const float* __restrict__ fcw,
                                             const float* __restrict__ fcb,
                                             unsigned short* __restrict__ fnorm,
                                             float* __restrict__ unary,
                                             float* __restrict__ coef0) {
  const int lane = threadIdx.x & 63;
  const int row = blockIdx.x * 4 + (threadIdx.x >> 6);
  const float* fr = feats + (size_t)row * 256;
  float4 v = *(const float4*)(fr + lane * 4);
  float4 w = *(const float4*)(fcw + lane * 4);
  float ssq = v.x * v.x + v.y * v.y + v.z * v.z + v.w * v.w;
  float dot = v.x * w.x + v.y * w.y + v.z * w.z + v.w * w.w;
#pragma unroll
  for (int o = 32; o; o >>= 1) { ssq += __shfl_xor(ssq, o); dot += __shfl_xor(dot, o); }
  float rfn = rsqrtf(ssq);
  *(ushort4*)(fnorm + (size_t)row * 256 + lane * 4) =
      make_ushort4(f2bf(v.x * rfn), f2bf(v.y * rfn), f2bf(v.z * rfn), f2bf(v.w * rfn));
  if (lane == 0) {
    float lg = dot + fcb[0];
    unary[row] = lg;
    coef0[row] = 1.f - 2.f / (1.f + __expf(-lg));
  }
}

// PP[i,j] = (fnorm_i . fnorm_j) * 0.5*(W[i,j]+W[j,i])  stored bf16
// Symmetric: only bi<=bj tile pairs; MFMA fragments loaded directly from
// global fnorm into EXPLICIT register arrays (32 loads in flight, one
// latency exposure), then 16 back-to-back MFMAs. No LDS/barrier in K-loop.
__global__ __launch_bounds__(256, 2) void ppbuild_sym(const unsigned short* __restrict__ fnorm,
                                                      const float* __restrict__ W,
                                                      unsigned short* __restrict__ PP) {
  const int bi = blockIdx.x, bj = blockIdx.y;
  if (bj < bi) return;
  const int i0 = bi * 64, j0 = bj * 64;
  __shared__ __align__(16) unsigned char shm[18944];  // union: Wt | OutD+OutT
  float (*Wt)[65] = (float(*)[65])shm;                // 64x65 fp32 = 16640 B
  unsigned short* OutD = (unsigned short*)shm;        // 64x74 ushort = 9472 B
  unsigned short* OutT = (unsigned short*)(shm + 9472);
  const int t = threadIdx.x;

  // stage transposed W block: Wt[j][i] = W[(j0+j)*N + i0+i]  (coalesced)
  {
    const int j = t >> 2, cb = (t & 3) * 16;
    const float* src = W + (size_t)(j0 + j) * NROWS + i0 + cb;
#pragma unroll
    for (int q = 0; q < 4; ++q) {
      float4 v = *(const float4*)(src + q * 4);
      Wt[j][cb + q * 4 + 0] = v.x; Wt[j][cb + q * 4 + 1] = v.y;
      Wt[j][cb + q * 4 + 2] = v.z; Wt[j][cb + q * 4 + 3] = v.w;
    }
  }

  const int lane = t & 63;
  const int wv = t >> 6;
  const int wi = wv >> 1, wj = wv & 1;
  const int khalf = lane >> 5;

  // fragment base: row = lane&31 within 32-row block, k = khalf*8 + e
  const unsigned short* pa = fnorm + (size_t)(i0 + wi * 32 + (lane & 31)) * 256 + khalf * 8;
  const unsigned short* pbr = fnorm + (size_t)(j0 + wj * 32 + (lane & 31)) * 256 + khalf * 8;

  // explicit full prefetch: 32 independent 16B loads in flight
  bf16x8 af[16], bfr[16];
#pragma unroll
  for (int s = 0; s < 16; ++s) {
    af[s]  = *(const bf16x8*)(pa + s * 16);
    bfr[s] = *(const bf16x8*)(pbr + s * 16);
  }
  f32x16 acc;
#pragma unroll
  for (int r = 0; r < 16; ++r) acc[r] = 0.f;
#pragma unroll
  for (int s = 0; s < 16; ++s)
    acc = __builtin_amdgcn_mfma_f32_32x32x16_bf16(af[s], bfr[s], acc, 0, 0, 0);

  __syncthreads();  // Wt writes visible before epilogue reads
  unsigned short pb[16];
#pragma unroll
  for (int r = 0; r < 16; ++r) {
    int rowl = (r & 3) + 8 * (r >> 2) + 4 * khalf;
    int coll = lane & 31;
    int il = wi * 32 + rowl, jl = wj * 32 + coll;
    float wd = W[(size_t)(i0 + il) * NROWS + (j0 + jl)];
    float ws = 0.5f * (wd + Wt[jl][il]);
    pb[r] = f2bf(acc[r] * ws);
  }
  __syncthreads();  // done reading Wt; reuse LDS for output bounce
#pragma unroll
  for (int r = 0; r < 16; ++r) {
    int rowl = (r & 3) + 8 * (r >> 2) + 4 * khalf;
    int coll = lane & 31;
    int il = wi * 32 + rowl, jl = wj * 32 + coll;
    OutD[il * 74 + jl] = pb[r];
    OutT[jl * 74 + il] = pb[r];
  }
  __syncthreads();
  const int row = t >> 3;      // 0..31
  const int seg = t & 7;       // 0..7
#pragma unroll
  for (int q = 0; q < 2; ++q) {
    int rr = row + q * 32;
    const unsigned int* pd = (const unsigned int*)(OutD + rr * 74 + seg * 8);
    const unsigned int* pt = (const unsigned int*)(OutT + rr * 74 + seg * 8);
    union { u16x8 v; unsigned int u[4]; } dd, tt;
#pragma unroll
    for (int k = 0; k < 4; ++k) { dd.u[k] = pd[k]; tt.u[k] = pt[k]; }
    *(u16x8*)(PP + (size_t)(i0 + rr) * NROWS + j0 + seg * 8) = dd.v;
    *(u16x8*)(PP + (size_t)(j0 + rr) * NROWS + i0 + seg * 8) = tt.v;
  }
}

// one row of E = PP @ coef; lg = unary + E; coef_out = 1-2*sigmoid(lg)
__global__ __launch_bounds__(256) void ppmv(const unsigned short* __restrict__ PP,
                                            const float* __restrict__ coef_in,
                                            const float* __restrict__ unary,
                                            float* __restrict__ coef_out,
                                            float* __restrict__ lg_out) {
  const int i = blockIdx.x;
  const unsigned short* row = PP + (size_t)i * NROWS;
  float acc = 0.f;
#pragma unroll
  for (int cc = 0; cc < 4; ++cc) {
    int j0 = (cc * 256 + threadIdx.x) * 8;
    u16x8 p = *(const u16x8*)(row + j0);
    float4 c0 = *(const float4*)(coef_in + j0);
    float4 c1 = *(const float4*)(coef_in + j0 + 4);
    acc += bf2f(p[0]) * c0.x + bf2f(p[1]) * c0.y + bf2f(p[2]) * c0.z + bf2f(p[3]) * c0.w;
    acc += bf2f(p[4]) * c1.x + bf2f(p[5]) * c1.y + bf2f(p[6]) * c1.z + bf2f(p[7]) * c1.w;
  }
#pragma unroll
  for (int o = 32; o; o >>= 1) acc += __shfl_xor(acc, o);
  __shared__ float red[4];
  if ((threadIdx.x & 63) == 0) red[threadIdx.x >> 6] = acc;
  __syncthreads();
  if (threadIdx.x == 0) {
    float tot = red[0] + red[1] + red[2] + red[3];
    float lg = unary[i] + tot;
    coef_out[i] = 1.f - 2.f / (1.f + __expf(-lg));
    if (lg_out) lg_out[i] = lg;
  }
}

extern "C" void kernel_launch(void* const* d_in, const int* in_sizes, int n_in,
                              void* d_out, int out_size, void* d_ws, size_t ws_size,
                              hipStream_t stream) {
  const float* x   = (const float*)d_in[0];
  const float* W   = (const float*)d_in[1];
  const float* W1  = (const float*)d_in[2];
  const float* g1  = (const float*)d_in[4];
  const float* be1 = (const float*)d_in[5];
  const float* W2  = (const float*)d_in[6];
  const float* g2  = (const float*)d_in[8];
  const float* be2 = (const float*)d_in[9];
  const float* fcw = (const float*)d_in[10];
  const float* fcb = (const float*)d_in[11];
  float* out = (float*)d_out;

  char* ws = (char*)d_ws;
  float* h      = (float*)(ws + 0);              // 8192*512*4  = 16 MB
  float* feats  = (float*)(ws + 16777216);       // 8192*256*4  = 8 MB
  float* p1s    = (float*)(ws + 25165824);       // 64*512*4
  float* p1q    = (float*)(ws + 25296896);       // 64*512*4
  float* p2s    = (float*)(ws + 25427968);       // 64*256*4
  float* p2q    = (float*)(ws + 25493504);       // 64*256*4
  float2* ab1   = (float2*)(ws + 25559040);      // 512*8
  float2* ab2   = (float2*)(ws + 25563136);      // 256*8
  unsigned short* fnorm = (unsigned short*)(ws + 25565184);  // 8192*256*2 = 4 MB
  float* unary  = (float*)(ws + 29759488);       // 8192*4
  float* coefA  = (float*)(ws + 29792256);       // 8192*4
  float* coefB  = (float*)(ws + 29825024);       // 8192*4
  unsigned short* PP = (unsigned short*)(ws + 29857792);     // 8192*8192*2 = 128 MB
  if (ws_size < (size_t)29857792 + (size_t)NROWS * NROWS * 2) return;

  // layer 1: h = x @ W1^T ; BN ; leaky
  gemm_bt<<<dim3(128, 8), 256, 0, stream>>>(x, W1, h, 8192, 512, 128);
  colstats<<<dim3(8, 64), 256, 0, stream>>>(h, 512, p1s, p1q);
  bn_finalize<<<2, 256, 0, stream>>>(p1s, p1q, g1, be1, ab1, 512);
  bn_act<<<4096, 256, 0, stream>>>(h, ab1, 511);
  // layer 2: feats = h @ W2^T ; BN ; leaky
  gemm_bt<<<dim3(128, 4), 256, 0, stream>>>(h, W2, feats, 8192, 256, 512);
  colstats<<<dim3(4, 64), 256, 0, stream>>>(feats, 256, p2s, p2q);
  bn_finalize<<<1, 256, 0, stream>>>(p2s, p2q, g2, be2, ab2, 256);
  bn_act<<<2048, 256, 0, stream>>>(feats, ab2, 255);
  // row norms + unary logits + coef0
  rowfn<<<2048, 256, 0, stream>>>(feats, fcw, fcb, fnorm, unary, coefA);
  // PP = sim * W_sym  (bf16), symmetric tile-pair build
  ppbuild_sym<<<dim3(128, 128), 256, 0, stream>>>(fnorm, W, PP);
  // 10 sequential matvec iterations
  float* cur = coefA; float* nxt = coefB;
  for (int it = 0; it < NITER; ++it) {
    ppmv<<<8192, 256, 0, stream>>>(PP, cur, unary, nxt, it == NITER - 1 ? out : nullptr);
    float* tmp = cur; cur = nxt; nxt = tmp;
  }
}

// Round 5
// 523.293 us; speedup vs baseline: 1.1218x; 1.0348x over previous
//
#include <hip/hip_runtime.h>
#include <hip/hip_bf16.h>

#define NROWS 8192
#define NITER 10

typedef __attribute__((ext_vector_type(8))) short bf16x8;
typedef __attribute__((ext_vector_type(8))) unsigned short u16x8;
typedef __attribute__((ext_vector_type(16))) float f32x16;

__device__ __forceinline__ float bf2f(unsigned short u) {
  union { float f; unsigned int i; } c; c.i = ((unsigned int)u) << 16; return c.f;
}
__device__ __forceinline__ unsigned short f2bf(float f) {
  unsigned int x = __float_as_uint(f);
  unsigned int r = (x + 0x7FFFu + ((x >> 16) & 1u)) >> 16;
  return (unsigned short)r;
}

// C[M,NN] = A[M,K] * B[NN,K]^T   (fp32, 64x64 tile, 4x4 per thread)
__global__ __launch_bounds__(256) void gemm_bt(const float* __restrict__ A,
                                               const float* __restrict__ B,
                                               float* __restrict__ C,
                                               int M, int NN, int K) {
  __shared__ float As[16][68];
  __shared__ float Bs[16][68];
  const int t = threadIdx.x;
  const int m0 = blockIdx.x * 64, n0 = blockIdx.y * 64;
  const int lr = t >> 2, lc = t & 3;
  const int ty = t >> 4, tx = t & 15;
  float acc[4][4];
#pragma unroll
  for (int i = 0; i < 4; ++i)
#pragma unroll
    for (int j = 0; j < 4; ++j) acc[i][j] = 0.f;
  for (int kt = 0; kt < K; kt += 16) {
    float4 av = *(const float4*)(A + (size_t)(m0 + lr) * K + kt + lc * 4);
    float4 bv = *(const float4*)(B + (size_t)(n0 + lr) * K + kt + lc * 4);
    __syncthreads();
    As[lc * 4 + 0][lr] = av.x; As[lc * 4 + 1][lr] = av.y;
    As[lc * 4 + 2][lr] = av.z; As[lc * 4 + 3][lr] = av.w;
    Bs[lc * 4 + 0][lr] = bv.x; Bs[lc * 4 + 1][lr] = bv.y;
    Bs[lc * 4 + 2][lr] = bv.z; Bs[lc * 4 + 3][lr] = bv.w;
    __syncthreads();
#pragma unroll
    for (int k = 0; k < 16; ++k) {
      float4 a4 = *(const float4*)&As[k][ty * 4];
      float4 b4 = *(const float4*)&Bs[k][tx * 4];
      float a[4] = {a4.x, a4.y, a4.z, a4.w};
      float b[4] = {b4.x, b4.y, b4.z, b4.w};
#pragma unroll
      for (int i = 0; i < 4; ++i)
#pragma unroll
        for (int j = 0; j < 4; ++j) acc[i][j] += a[i] * b[j];
    }
  }
#pragma unroll
  for (int i = 0; i < 4; ++i) {
    float4 o = make_float4(acc[i][0], acc[i][1], acc[i][2], acc[i][3]);
    *(float4*)(C + (size_t)(m0 + ty * 4 + i) * NN + n0 + tx * 4) = o;
  }
}

// per-column partial sums (deterministic two-stage BN stats)
__global__ __launch_bounds__(256) void colstats(const float* __restrict__ in, int C,
                                                float* __restrict__ pS,
                                                float* __restrict__ pSS) {
  const int t = threadIdx.x;
  const int col = blockIdx.x * 64 + (t & 63);
  const int rp = t >> 6;
  const int r0 = blockIdx.y * 128;
  float s = 0.f, ss = 0.f;
  for (int r = rp; r < 128; r += 4) {
    float v = in[(size_t)(r0 + r) * C + col];
    s += v; ss += v * v;
  }
  __shared__ float lS[4][64], lQ[4][64];
  lS[rp][t & 63] = s; lQ[rp][t & 63] = ss;
  __syncthreads();
  if (t < 64) {
    float ts = lS[0][t] + lS[1][t] + lS[2][t] + lS[3][t];
    float tq = lQ[0][t] + lQ[1][t] + lQ[2][t] + lQ[3][t];
    pS[(size_t)blockIdx.y * C + blockIdx.x * 64 + t] = ts;
    pSS[(size_t)blockIdx.y * C + blockIdx.x * 64 + t] = tq;
  }
}

__global__ void bn_finalize(const float* __restrict__ pS, const float* __restrict__ pSS,
                            const float* __restrict__ g, const float* __restrict__ be,
                            float2* __restrict__ ab, int C) {
  int c = blockIdx.x * 256 + threadIdx.x;
  if (c >= C) return;
  float s = 0.f, q = 0.f;
  for (int r = 0; r < 64; ++r) { s += pS[r * C + c]; q += pSS[r * C + c]; }
  const float invM = 1.f / 8192.f;
  float mu = s * invM;
  float var = q * invM - mu * mu;
  float rstd = rsqrtf(var + 1e-5f);
  float a = g[c] * rstd;
  ab[c] = make_float2(a, be[c] - mu * a);
}

// in-place: h = leaky_relu(a*h + b), per column
__global__ __launch_bounds__(256) void bn_act(float* __restrict__ h,
                                              const float2* __restrict__ ab,
                                              int Cmask) {
  size_t idx = (size_t)blockIdx.x * 256 + threadIdx.x;
  float4 v = ((const float4*)h)[idx];
  int cb = (int)((idx * 4) & (size_t)Cmask);
  float2 a0 = ab[cb], a1 = ab[cb + 1], a2 = ab[cb + 2], a3 = ab[cb + 3];
  float r0 = a0.x * v.x + a0.y; r0 = r0 >= 0.f ? r0 : 0.01f * r0;
  float r1 = a1.x * v.y + a1.y; r1 = r1 >= 0.f ? r1 : 0.01f * r1;
  float r2 = a2.x * v.z + a2.y; r2 = r2 >= 0.f ? r2 : 0.01f * r2;
  float r3 = a3.x * v.w + a3.y; r3 = r3 >= 0.f ? r3 : 0.01f * r3;
  ((float4*)h)[idx] = make_float4(r0, r1, r2, r3);
}

// per row: fn, unary logit, coef0; write row-normalized feats as bf16
__global__ __launch_bounds__(256) void rowfn(const float* __restrict__ feats,
                                             const float* __restrict__ fcw,
                                             const float* __restrict__ fcb,
                                             unsigned short* __restrict__ fnorm,
                                             float* __restrict__ unary,
                                             float* __restrict__ coef0) {
  const int lane = threadIdx.x & 63;
  const int row = blockIdx.x * 4 + (threadIdx.x >> 6);
  const float* fr = feats + (size_t)row * 256;
  float4 v = *(const float4*)(fr + lane * 4);
  float4 w = *(const float4*)(fcw + lane * 4);
  float ssq = v.x * v.x + v.y * v.y + v.z * v.z + v.w * v.w;
  float dot = v.x * w.x + v.y * w.y + v.z * w.z + v.w * w.w;
#pragma unroll
  for (int o = 32; o; o >>= 1) { ssq += __shfl_xor(ssq, o); dot += __shfl_xor(dot, o); }
  float rfn = rsqrtf(ssq);
  *(ushort4*)(fnorm + (size_t)row * 256 + lane * 4) =
      make_ushort4(f2bf(v.x * rfn), f2bf(v.y * rfn), f2bf(v.z * rfn), f2bf(v.w * rfn));
  if (lane == 0) {
    float lg = dot + fcb[0];
    unary[row] = lg;
    coef0[row] = 1.f - 2.f / (1.f + __expf(-lg));
  }
}

// PP[i,j] = (fnorm_i . fnorm_j) * 0.5*(W[i,j]+W[j,i])  stored bf16
// Symmetric: only bi<=bj tile pairs; fragments loaded directly from global
// fnorm into registers; sched_barrier(0) pins ALL 32 loads before the MFMA
// chain so they are in flight together (one latency exposure per wave).
__global__ __launch_bounds__(256, 2) void ppbuild_sym(const unsigned short* __restrict__ fnorm,
                                                      const float* __restrict__ W,
                                                      unsigned short* __restrict__ PP) {
  const int bi = blockIdx.x, bj = blockIdx.y;
  if (bj < bi) return;
  const int i0 = bi * 64, j0 = bj * 64;
  __shared__ __align__(16) unsigned char shm[18944];  // union: Wt | OutD+OutT
  float (*Wt)[65] = (float(*)[65])shm;                // 64x65 fp32 = 16640 B
  unsigned short* OutD = (unsigned short*)shm;        // 64x74 ushort = 9472 B
  unsigned short* OutT = (unsigned short*)(shm + 9472);
  const int t = threadIdx.x;

  // stage transposed W block: Wt[j][i] = W[(j0+j)*N + i0+i]  (coalesced)
  {
    const int j = t >> 2, cb = (t & 3) * 16;
    const float* src = W + (size_t)(j0 + j) * NROWS + i0 + cb;
#pragma unroll
    for (int q = 0; q < 4; ++q) {
      float4 v = *(const float4*)(src + q * 4);
      Wt[j][cb + q * 4 + 0] = v.x; Wt[j][cb + q * 4 + 1] = v.y;
      Wt[j][cb + q * 4 + 2] = v.z; Wt[j][cb + q * 4 + 3] = v.w;
    }
  }

  const int lane = t & 63;
  const int wv = t >> 6;
  const int wi = wv >> 1, wj = wv & 1;
  const int khalf = lane >> 5;

  // fragment base: row = lane&31 within 32-row block, k = khalf*8 + e
  const unsigned short* pa = fnorm + (size_t)(i0 + wi * 32 + (lane & 31)) * 256 + khalf * 8;
  const unsigned short* pbr = fnorm + (size_t)(j0 + wj * 32 + (lane & 31)) * 256 + khalf * 8;

  // explicit full prefetch: 32 independent 16B loads, pinned before MFMAs
  bf16x8 af[16], bfr[16];
#pragma unroll
  for (int s = 0; s < 16; ++s) {
    af[s]  = *(const bf16x8*)(pa + s * 16);
    bfr[s] = *(const bf16x8*)(pbr + s * 16);
  }
  __builtin_amdgcn_sched_barrier(0);  // nothing crosses: loads stay hoisted
  f32x16 acc;
#pragma unroll
  for (int r = 0; r < 16; ++r) acc[r] = 0.f;
#pragma unroll
  for (int s = 0; s < 16; ++s)
    acc = __builtin_amdgcn_mfma_f32_32x32x16_bf16(af[s], bfr[s], acc, 0, 0, 0);

  __syncthreads();  // Wt writes visible before epilogue reads
  unsigned short pb[16];
#pragma unroll
  for (int r = 0; r < 16; ++r) {
    int rowl = (r & 3) + 8 * (r >> 2) + 4 * khalf;
    int coll = lane & 31;
    int il = wi * 32 + rowl, jl = wj * 32 + coll;
    float wd = W[(size_t)(i0 + il) * NROWS + (j0 + jl)];
    float ws = 0.5f * (wd + Wt[jl][il]);
    pb[r] = f2bf(acc[r] * ws);
  }
  __syncthreads();  // done reading Wt; reuse LDS for output bounce
#pragma unroll
  for (int r = 0; r < 16; ++r) {
    int rowl = (r & 3) + 8 * (r >> 2) + 4 * khalf;
    int coll = lane & 31;
    int il = wi * 32 + rowl, jl = wj * 32 + coll;
    OutD[il * 74 + jl] = pb[r];
    OutT[jl * 74 + il] = pb[r];
  }
  __syncthreads();
  const int row = t >> 3;      // 0..31
  const int seg = t & 7;       // 0..7
#pragma unroll
  for (int q = 0; q < 2; ++q) {
    int rr = row + q * 32;
    const unsigned int* pd = (const unsigned int*)(OutD + rr * 74 + seg * 8);
    const unsigned int* pt = (const unsigned int*)(OutT + rr * 74 + seg * 8);
    union { u16x8 v; unsigned int u[4]; } dd, tt;
#pragma unroll
    for (int k = 0; k < 4; ++k) { dd.u[k] = pd[k]; tt.u[k] = pt[k]; }
    *(u16x8*)(PP + (size_t)(i0 + rr) * NROWS + j0 + seg * 8) = dd.v;
    *(u16x8*)(PP + (size_t)(j0 + rr) * NROWS + i0 + seg * 8) = tt.v;
  }
}

// one row of E = PP @ coef; lg = unary + E; coef_out = 1-2*sigmoid(lg)
__global__ __launch_bounds__(256) void ppmv(const unsigned short* __restrict__ PP,
                                            const float* __restrict__ coef_in,
                                            const float* __restrict__ unary,
                                            float* __restrict__ coef_out,
                                            float* __restrict__ lg_out) {
  const int i = blockIdx.x;
  const unsigned short* row = PP + (size_t)i * NROWS;
  float acc = 0.f;
#pragma unroll
  for (int cc = 0; cc < 4; ++cc) {
    int j0 = (cc * 256 + threadIdx.x) * 8;
    u16x8 p = *(const u16x8*)(row + j0);
    float4 c0 = *(const float4*)(coef_in + j0);
    float4 c1 = *(const float4*)(coef_in + j0 + 4);
    acc += bf2f(p[0]) * c0.x + bf2f(p[1]) * c0.y + bf2f(p[2]) * c0.z + bf2f(p[3]) * c0.w;
    acc += bf2f(p[4]) * c1.x + bf2f(p[5]) * c1.y + bf2f(p[6]) * c1.z + bf2f(p[7]) * c1.w;
  }
#pragma unroll
  for (int o = 32; o; o >>= 1) acc += __shfl_xor(acc, o);
  __shared__ float red[4];
  if ((threadIdx.x & 63) == 0) red[threadIdx.x >> 6] = acc;
  __syncthreads();
  if (threadIdx.x == 0) {
    float tot = red[0] + red[1] + red[2] + red[3];
    float lg = unary[i] + tot;
    coef_out[i] = 1.f - 2.f / (1.f + __expf(-lg));
    if (lg_out) lg_out[i] = lg;
  }
}

extern "C" void kernel_launch(void* const* d_in, const int* in_sizes, int n_in,
                              void* d_out, int out_size, void* d_ws, size_t ws_size,
                              hipStream_t stream) {
  const float* x   = (const float*)d_in[0];
  const float* W   = (const float*)d_in[1];
  const float* W1  = (const float*)d_in[2];
  const float* g1  = (const float*)d_in[4];
  const float* be1 = (const float*)d_in[5];
  const float* W2  = (const float*)d_in[6];
  const float* g2  = (const float*)d_in[8];
  const float* be2 = (const float*)d_in[9];
  const float* fcw = (const float*)d_in[10];
  const float* fcb = (const float*)d_in[11];
  float* out = (float*)d_out;

  char* ws = (char*)d_ws;
  float* h      = (float*)(ws + 0);              // 8192*512*4  = 16 MB
  float* feats  = (float*)(ws + 16777216);       // 8192*256*4  = 8 MB
  float* p1s    = (float*)(ws + 25165824);       // 64*512*4
  float* p1q    = (float*)(ws + 25296896);       // 64*512*4
  float* p2s    = (float*)(ws + 25427968);       // 64*256*4
  float* p2q    = (float*)(ws + 25493504);       // 64*256*4
  float2* ab1   = (float2*)(ws + 25559040);      // 512*8
  float2* ab2   = (float2*)(ws + 25563136);      // 256*8
  unsigned short* fnorm = (unsigned short*)(ws + 25565184);  // 8192*256*2 = 4 MB
  float* unary  = (float*)(ws + 29759488);       // 8192*4
  float* coefA  = (float*)(ws + 29792256);       // 8192*4
  float* coefB  = (float*)(ws + 29825024);       // 8192*4
  unsigned short* PP = (unsigned short*)(ws + 29857792);     // 8192*8192*2 = 128 MB
  if (ws_size < (size_t)29857792 + (size_t)NROWS * NROWS * 2) return;

  // layer 1: h = x @ W1^T ; BN ; leaky
  gemm_bt<<<dim3(128, 8), 256, 0, stream>>>(x, W1, h, 8192, 512, 128);
  colstats<<<dim3(8, 64), 256, 0, stream>>>(h, 512, p1s, p1q);
  bn_finalize<<<2, 256, 0, stream>>>(p1s, p1q, g1, be1, ab1, 512);
  bn_act<<<4096, 256, 0, stream>>>(h, ab1, 511);
  // layer 2: feats = h @ W2^T ; BN ; leaky
  gemm_bt<<<dim3(128, 4), 256, 0, stream>>>(h, W2, feats, 8192, 256, 512);
  colstats<<<dim3(4, 64), 256, 0, stream>>>(feats, 256, p2s, p2q);
  bn_finalize<<<1, 256, 0, stream>>>(p2s, p2q, g2, be2, ab2, 256);
  bn_act<<<2048, 256, 0, stream>>>(feats, ab2, 255);
  // row norms + unary logits + coef0
  rowfn<<<2048, 256, 0, stream>>>(feats, fcw, fcb, fnorm, unary, coefA);
  // PP = sim * W_sym  (bf16), symmetric tile-pair build
  ppbuild_sym<<<dim3(128, 128), 256, 0, stream>>>(fnorm, W, PP);
  // 10 sequential matvec iterations
  float* cur = coefA; float* nxt = coefB;
  for (int it = 0; it < NITER; ++it) {
    ppmv<<<8192, 256, 0, stream>>>(PP, cur, unary, nxt, it == NITER - 1 ? out : nullptr);
    float* tmp = cur; cur = nxt; nxt = tmp;
  }
}

// Round 6
// 421.929 us; speedup vs baseline: 1.3913x; 1.2402x over previous
//
#include <hip/hip_runtime.h>
#include <hip/hip_bf16.h>

#define NROWS 8192
#define NITER 10

typedef __attribute__((ext_vector_type(8))) short bf16x8;
typedef __attribute__((ext_vector_type(8))) unsigned short u16x8;
typedef __attribute__((ext_vector_type(16))) float f32x16;

__device__ __forceinline__ float bf2f(unsigned short u) {
  union { float f; unsigned int i; } c; c.i = ((unsigned int)u) << 16; return c.f;
}
__device__ __forceinline__ unsigned short f2bf(float f) {
  unsigned int x = __float_as_uint(f);
  unsigned int r = (x + 0x7FFFu + ((x >> 16) & 1u)) >> 16;
  return (unsigned short)r;
}

// C[M,NN] = A[M,K] * B[NN,K]^T   (fp32, 64x64 tile, 4x4 per thread)
__global__ __launch_bounds__(256) void gemm_bt(const float* __restrict__ A,
                                               const float* __restrict__ B,
                                               float* __restrict__ C,
                                               int M, int NN, int K) {
  __shared__ float As[16][68];
  __shared__ float Bs[16][68];
  const int t = threadIdx.x;
  const int m0 = blockIdx.x * 64, n0 = blockIdx.y * 64;
  const int lr = t >> 2, lc = t & 3;
  const int ty = t >> 4, tx = t & 15;
  float acc[4][4];
#pragma unroll
  for (int i = 0; i < 4; ++i)
#pragma unroll
    for (int j = 0; j < 4; ++j) acc[i][j] = 0.f;
  for (int kt = 0; kt < K; kt += 16) {
    float4 av = *(const float4*)(A + (size_t)(m0 + lr) * K + kt + lc * 4);
    float4 bv = *(const float4*)(B + (size_t)(n0 + lr) * K + kt + lc * 4);
    __syncthreads();
    As[lc * 4 + 0][lr] = av.x; As[lc * 4 + 1][lr] = av.y;
    As[lc * 4 + 2][lr] = av.z; As[lc * 4 + 3][lr] = av.w;
    Bs[lc * 4 + 0][lr] = bv.x; Bs[lc * 4 + 1][lr] = bv.y;
    Bs[lc * 4 + 2][lr] = bv.z; Bs[lc * 4 + 3][lr] = bv.w;
    __syncthreads();
#pragma unroll
    for (int k = 0; k < 16; ++k) {
      float4 a4 = *(const float4*)&As[k][ty * 4];
      float4 b4 = *(const float4*)&Bs[k][tx * 4];
      float a[4] = {a4.x, a4.y, a4.z, a4.w};
      float b[4] = {b4.x, b4.y, b4.z, b4.w};
#pragma unroll
      for (int i = 0; i < 4; ++i)
#pragma unroll
        for (int j = 0; j < 4; ++j) acc[i][j] += a[i] * b[j];
    }
  }
#pragma unroll
  for (int i = 0; i < 4; ++i) {
    float4 o = make_float4(acc[i][0], acc[i][1], acc[i][2], acc[i][3]);
    *(float4*)(C + (size_t)(m0 + ty * 4 + i) * NN + n0 + tx * 4) = o;
  }
}

// per-column partial sums (deterministic two-stage BN stats)
__global__ __launch_bounds__(256) void colstats(const float* __restrict__ in, int C,
                                                float* __restrict__ pS,
                                                float* __restrict__ pSS) {
  const int t = threadIdx.x;
  const int col = blockIdx.x * 64 + (t & 63);
  const int rp = t >> 6;
  const int r0 = blockIdx.y * 128;
  float s = 0.f, ss = 0.f;
  for (int r = rp; r < 128; r += 4) {
    float v = in[(size_t)(r0 + r) * C + col];
    s += v; ss += v * v;
  }
  __shared__ float lS[4][64], lQ[4][64];
  lS[rp][t & 63] = s; lQ[rp][t & 63] = ss;
  __syncthreads();
  if (t < 64) {
    float ts = lS[0][t] + lS[1][t] + lS[2][t] + lS[3][t];
    float tq = lQ[0][t] + lQ[1][t] + lQ[2][t] + lQ[3][t];
    pS[(size_t)blockIdx.y * C + blockIdx.x * 64 + t] = ts;
    pSS[(size_t)blockIdx.y * C + blockIdx.x * 64 + t] = tq;
  }
}

__global__ void bn_finalize(const float* __restrict__ pS, const float* __restrict__ pSS,
                            const float* __restrict__ g, const float* __restrict__ be,
                            float2* __restrict__ ab, int C) {
  int c = blockIdx.x * 256 + threadIdx.x;
  if (c >= C) return;
  float s = 0.f, q = 0.f;
  for (int r = 0; r < 64; ++r) { s += pS[r * C + c]; q += pSS[r * C + c]; }
  const float invM = 1.f / 8192.f;
  float mu = s * invM;
  float var = q * invM - mu * mu;
  float rstd = rsqrtf(var + 1e-5f);
  float a = g[c] * rstd;
  ab[c] = make_float2(a, be[c] - mu * a);
}

// in-place: h = leaky_relu(a*h + b), per column
__global__ __launch_bounds__(256) void bn_act(float* __restrict__ h,
                                              const float2* __restrict__ ab,
                                              int Cmask) {
  size_t idx = (size_t)blockIdx.x * 256 + threadIdx.x;
  float4 v = ((const float4*)h)[idx];
  int cb = (int)((idx * 4) & (size_t)Cmask);
  float2 a0 = ab[cb], a1 = ab[cb + 1], a2 = ab[cb + 2], a3 = ab[cb + 3];
  float r0 = a0.x * v.x + a0.y; r0 = r0 >= 0.f ? r0 : 0.01f * r0;
  float r1 = a1.x * v.y + a1.y; r1 = r1 >= 0.f ? r1 : 0.01f * r1;
  float r2 = a2.x * v.z + a2.y; r2 = r2 >= 0.f ? r2 : 0.01f * r2;
  float r3 = a3.x * v.w + a3.y; r3 = r3 >= 0.f ? r3 : 0.01f * r3;
  ((float4*)h)[idx] = make_float4(r0, r1, r2, r3);
}

// per row: fn, unary logit, coef0; write row-normalized feats as bf16
__global__ __launch_bounds__(256) void rowfn(const float* __restrict__ feats,
                                             const float* __restrict__ fcw,
                                             const float* __restrict__ fcb,
                                             unsigned short* __restrict__ fnorm,
                                             float* __restrict__ unary,
                                             float* __restrict__ coef0) {
  const int lane = threadIdx.x & 63;
  const int row = blockIdx.x * 4 + (threadIdx.x >> 6);
  const float* fr = feats + (size_t)row * 256;
  float4 v = *(const float4*)(fr + lane * 4);
  float4 w = *(const float4*)(fcw + lane * 4);
  float ssq = v.x * v.x + v.y * v.y + v.z * v.z + v.w * v.w;
  float dot = v.x * w.x + v.y * w.y + v.z * w.z + v.w * w.w;
#pragma unroll
  for (int o = 32; o; o >>= 1) { ssq += __shfl_xor(ssq, o); dot += __shfl_xor(dot, o); }
  float rfn = rsqrtf(ssq);
  *(ushort4*)(fnorm + (size_t)row * 256 + lane * 4) =
      make_ushort4(f2bf(v.x * rfn), f2bf(v.y * rfn), f2bf(v.z * rfn), f2bf(v.w * rfn));
  if (lane == 0) {
    float lg = dot + fcb[0];
    unary[row] = lg;
    coef0[row] = 1.f - 2.f / (1.f + __expf(-lg));
  }
}

// PP[i,j] = (fnorm_i . fnorm_j) * 0.5*(W[i,j]+W[j,i])  stored bf16
// Triangular grid (8256 blocks, no wasted dispatches). LDS time-multiplexed:
// phase1 Asw/Bsw (MFMA staging) -> phase2 Wt (fp32 transpose) -> phase3
// OutD/OutT (store bounce). Peak 18.9KB -> ~7 blocks/CU.
__global__ __launch_bounds__(256) void ppbuild_sym(const unsigned short* __restrict__ fnorm,
                                                   const float* __restrict__ W,
                                                   unsigned short* __restrict__ PP) {
  // tril inversion: S(b) = b*(257-b)/2 tiles before row b
#define TRIS(b) ((b) * (257 - (b)) / 2)
  const int L = blockIdx.x;
  int bi = (int)((257.0f - sqrtf((float)(66049 - 8 * L))) * 0.5f);
  if (bi > 127) bi = 127;
  if (bi < 0) bi = 0;
  while (bi < 127 && TRIS(bi + 1) <= L) ++bi;
  while (bi > 0 && TRIS(bi) > L) --bi;
  const int bj = bi + (L - TRIS(bi));
  const int i0 = bi * 64, j0 = bj * 64;

  __shared__ __align__(16) unsigned char shm[18944];
  unsigned short* Asw = (unsigned short*)shm;          // phase 1: 64x64
  unsigned short* Bsw = (unsigned short*)shm + 4736;   // phase 1: 64x64
  float (*Wt)[68] = (float(*)[68])shm;                 // phase 2: 64x68 fp32
  unsigned short* OutD = (unsigned short*)shm;         // phase 3: 64x74
  unsigned short* OutT = (unsigned short*)shm + 4736;  // phase 3: 64x74

  const int t = threadIdx.x;
  const int lane = t & 63;
  const int wv = t >> 6;
  const int wi = wv >> 1, wj = wv & 1;
  const int khalf = lane >> 5;

  f32x16 acc;
#pragma unroll
  for (int r = 0; r < 16; ++r) acc[r] = 0.f;

  const int lrow = t >> 2;        // 0..63
  const int lgp = (t & 3) * 2;    // 8-ushort group 0,2,4,6
  const int arow = wi * 32 + (lane & 31);
  const int brow = wj * 32 + (lane & 31);
#pragma unroll 1
  for (int c = 0; c < 4; ++c) {   // K chunks of 64
    const unsigned short* sa = fnorm + (size_t)(i0 + lrow) * 256 + c * 64 + lgp * 8;
    const unsigned short* sb = fnorm + (size_t)(j0 + lrow) * 256 + c * 64 + lgp * 8;
    u16x8 va0 = *(const u16x8*)(sa);
    u16x8 va1 = *(const u16x8*)(sa + 8);
    u16x8 vb0 = *(const u16x8*)(sb);
    u16x8 vb1 = *(const u16x8*)(sb + 8);
    __syncthreads();
    int s0 = (lgp ^ (lrow & 7)) * 8;
    int s1 = ((lgp + 1) ^ (lrow & 7)) * 8;
    *(u16x8*)&Asw[lrow * 64 + s0] = va0;
    *(u16x8*)&Asw[lrow * 64 + s1] = va1;
    *(u16x8*)&Bsw[lrow * 64 + s0] = vb0;
    *(u16x8*)&Bsw[lrow * 64 + s1] = vb1;
    __syncthreads();
#pragma unroll
    for (int s = 0; s < 4; ++s) {
      int slot = s * 2 + khalf;
      bf16x8 a = *(const bf16x8*)&Asw[arow * 64 + ((slot ^ (arow & 7)) * 8)];
      bf16x8 b = *(const bf16x8*)&Bsw[brow * 64 + ((slot ^ (brow & 7)) * 8)];
      acc = __builtin_amdgcn_mfma_f32_32x32x16_bf16(a, b, acc, 0, 0, 0);
    }
  }

  // phase 2: stage transposed W block into same LDS
  __syncthreads();
  {
    const int j = t >> 2, cb = (t & 3) * 16;
    const float* src = W + (size_t)(j0 + j) * NROWS + i0 + cb;
#pragma unroll
    for (int q = 0; q < 4; ++q) {
      float4 v = *(const float4*)(src + q * 4);
      Wt[j][cb + q * 4 + 0] = v.x; Wt[j][cb + q * 4 + 1] = v.y;
      Wt[j][cb + q * 4 + 2] = v.z; Wt[j][cb + q * 4 + 3] = v.w;
    }
  }
  __syncthreads();
  unsigned short pb[16];
#pragma unroll
  for (int r = 0; r < 16; ++r) {
    int rowl = (r & 3) + 8 * (r >> 2) + 4 * khalf;
    int coll = lane & 31;
    int il = wi * 32 + rowl, jl = wj * 32 + coll;
    float wd = W[(size_t)(i0 + il) * NROWS + (j0 + jl)];
    float ws = 0.5f * (wd + Wt[jl][il]);
    pb[r] = f2bf(acc[r] * ws);
  }
  // phase 3: bounce both tiles through LDS for coalesced stores
  __syncthreads();
#pragma unroll
  for (int r = 0; r < 16; ++r) {
    int rowl = (r & 3) + 8 * (r >> 2) + 4 * khalf;
    int coll = lane & 31;
    int il = wi * 32 + rowl, jl = wj * 32 + coll;
    OutD[il * 74 + jl] = pb[r];
    OutT[jl * 74 + il] = pb[r];
  }
  __syncthreads();
  const int row = t >> 3;      // 0..31
  const int seg = t & 7;       // 0..7
#pragma unroll
  for (int q = 0; q < 2; ++q) {
    int rr = row + q * 32;
    const unsigned int* pd = (const unsigned int*)(OutD + rr * 74 + seg * 8);
    const unsigned int* pt = (const unsigned int*)(OutT + rr * 74 + seg * 8);
    union { u16x8 v; unsigned int u[4]; } dd, tt;
#pragma unroll
    for (int k = 0; k < 4; ++k) { dd.u[k] = pd[k]; tt.u[k] = pt[k]; }
    *(u16x8*)(PP + (size_t)(i0 + rr) * NROWS + j0 + seg * 8) = dd.v;
    *(u16x8*)(PP + (size_t)(j0 + rr) * NROWS + i0 + seg * 8) = tt.v;
  }
#undef TRIS
}

// one row of E = PP @ coef; lg = unary + E; coef_out = 1-2*sigmoid(lg)
__global__ __launch_bounds__(256) void ppmv(const unsigned short* __restrict__ PP,
                                            const float* __restrict__ coef_in,
                                            const float* __restrict__ unary,
                                            float* __restrict__ coef_out,
                                            float* __restrict__ lg_out) {
  const int i = blockIdx.x;
  const unsigned short* row = PP + (size_t)i * NROWS;
  float acc = 0.f;
#pragma unroll
  for (int cc = 0; cc < 4; ++cc) {
    int j0 = (cc * 256 + threadIdx.x) * 8;
    u16x8 p = *(const u16x8*)(row + j0);
    float4 c0 = *(const float4*)(coef_in + j0);
    float4 c1 = *(const float4*)(coef_in + j0 + 4);
    acc += bf2f(p[0]) * c0.x + bf2f(p[1]) * c0.y + bf2f(p[2]) * c0.z + bf2f(p[3]) * c0.w;
    acc += bf2f(p[4]) * c1.x + bf2f(p[5]) * c1.y + bf2f(p[6]) * c1.z + bf2f(p[7]) * c1.w;
  }
#pragma unroll
  for (int o = 32; o; o >>= 1) acc += __shfl_xor(acc, o);
  __shared__ float red[4];
  if ((threadIdx.x & 63) == 0) red[threadIdx.x >> 6] = acc;
  __syncthreads();
  if (threadIdx.x == 0) {
    float tot = red[0] + red[1] + red[2] + red[3];
    float lg = unary[i] + tot;
    coef_out[i] = 1.f - 2.f / (1.f + __expf(-lg));
    if (lg_out) lg_out[i] = lg;
  }
}

extern "C" void kernel_launch(void* const* d_in, const int* in_sizes, int n_in,
                              void* d_out, int out_size, void* d_ws, size_t ws_size,
                              hipStream_t stream) {
  const float* x   = (const float*)d_in[0];
  const float* W   = (const float*)d_in[1];
  const float* W1  = (const float*)d_in[2];
  const float* g1  = (const float*)d_in[4];
  const float* be1 = (const float*)d_in[5];
  const float* W2  = (const float*)d_in[6];
  const float* g2  = (const float*)d_in[8];
  const float* be2 = (const float*)d_in[9];
  const float* fcw = (const float*)d_in[10];
  const float* fcb = (const float*)d_in[11];
  float* out = (float*)d_out;

  char* ws = (char*)d_ws;
  float* h      = (float*)(ws + 0);              // 8192*512*4  = 16 MB
  float* feats  = (float*)(ws + 16777216);       // 8192*256*4  = 8 MB
  float* p1s    = (float*)(ws + 25165824);       // 64*512*4
  float* p1q    = (float*)(ws + 25296896);       // 64*512*4
  float* p2s    = (float*)(ws + 25427968);       // 64*256*4
  float* p2q    = (float*)(ws + 25493504);       // 64*256*4
  float2* ab1   = (float2*)(ws + 25559040);      // 512*8
  float2* ab2   = (float2*)(ws + 25563136);      // 256*8
  unsigned short* fnorm = (unsigned short*)(ws + 25565184);  // 8192*256*2 = 4 MB
  float* unary  = (float*)(ws + 29759488);       // 8192*4
  float* coefA  = (float*)(ws + 29792256);       // 8192*4
  float* coefB  = (float*)(ws + 29825024);       // 8192*4
  unsigned short* PP = (unsigned short*)(ws + 29857792);     // 8192*8192*2 = 128 MB
  if (ws_size < (size_t)29857792 + (size_t)NROWS * NROWS * 2) return;

  // layer 1: h = x @ W1^T ; BN ; leaky
  gemm_bt<<<dim3(128, 8), 256, 0, stream>>>(x, W1, h, 8192, 512, 128);
  colstats<<<dim3(8, 64), 256, 0, stream>>>(h, 512, p1s, p1q);
  bn_finalize<<<2, 256, 0, stream>>>(p1s, p1q, g1, be1, ab1, 512);
  bn_act<<<4096, 256, 0, stream>>>(h, ab1, 511);
  // layer 2: feats = h @ W2^T ; BN ; leaky
  gemm_bt<<<dim3(128, 4), 256, 0, stream>>>(h, W2, feats, 8192, 256, 512);
  colstats<<<dim3(4, 64), 256, 0, stream>>>(feats, 256, p2s, p2q);
  bn_finalize<<<1, 256, 0, stream>>>(p2s, p2q, g2, be2, ab2, 256);
  bn_act<<<2048, 256, 0, stream>>>(feats, ab2, 255);
  // row norms + unary logits + coef0
  rowfn<<<2048, 256, 0, stream>>>(feats, fcw, fcb, fnorm, unary, coefA);
  // PP = sim * W_sym  (bf16), triangular tile grid
  ppbuild_sym<<<8256, 256, 0, stream>>>(fnorm, W, PP);
  // 10 sequential matvec iterations
  float* cur = coefA; float* nxt = coefB;
  for (int it = 0; it < NITER; ++it) {
    ppmv<<<8192, 256, 0, stream>>>(PP, cur, unary, nxt, it == NITER - 1 ? out : nullptr);
    float* tmp = cur; cur = nxt; nxt = tmp;
  }
}

// Round 7
// 378.361 us; speedup vs baseline: 1.5515x; 1.1151x over previous
//
#include <hip/hip_runtime.h>
#include <hip/hip_bf16.h>

#define NROWS 8192
#define NITER 10

typedef __attribute__((ext_vector_type(8))) short bf16x8;
typedef __attribute__((ext_vector_type(8))) unsigned short u16x8;
typedef __attribute__((ext_vector_type(16))) float f32x16;

__device__ __forceinline__ float bf2f(unsigned short u) {
  union { float f; unsigned int i; } c; c.i = ((unsigned int)u) << 16; return c.f;
}
__device__ __forceinline__ unsigned short f2bf(float f) {
  unsigned int x = __float_as_uint(f);
  unsigned int r = (x + 0x7FFFu + ((x >> 16) & 1u)) >> 16;
  return (unsigned short)r;
}

// fp32 -> bf16 cast, 8 elems/thread
__global__ __launch_bounds__(256) void cast_bf16(const float* __restrict__ in,
                                                 unsigned short* __restrict__ out,
                                                 int n8) {
  int idx = blockIdx.x * 256 + threadIdx.x;
  if (idx >= n8) return;
  const float4* p = (const float4*)in + (size_t)idx * 2;
  float4 a = p[0], b = p[1];
  u16x8 o;
  o[0] = f2bf(a.x); o[1] = f2bf(a.y); o[2] = f2bf(a.z); o[3] = f2bf(a.w);
  o[4] = f2bf(b.x); o[5] = f2bf(b.y); o[6] = f2bf(b.z); o[7] = f2bf(b.w);
  *(u16x8*)(out + (size_t)idx * 8) = o;
}

// C[M,NN] = A[M,K] @ B[NN,K]^T, bf16 inputs, fp32 out. 64x64 tile, 4 waves,
// MFMA 32x32x16, swizzled LDS staging (same structure as ppbuild_sym).
__global__ __launch_bounds__(256) void gemm_bt_mfma(const unsigned short* __restrict__ A,
                                                    const unsigned short* __restrict__ B,
                                                    float* __restrict__ C,
                                                    int NN, int K) {
  __shared__ __align__(16) unsigned short Asw[4096];
  __shared__ __align__(16) unsigned short Bsw[4096];
  const int i0 = blockIdx.x * 64, j0 = blockIdx.y * 64;
  const int t = threadIdx.x;
  const int lane = t & 63;
  const int wv = t >> 6;
  const int wi = wv >> 1, wj = wv & 1;
  const int khalf = lane >> 5;

  f32x16 acc;
#pragma unroll
  for (int r = 0; r < 16; ++r) acc[r] = 0.f;

  const int lrow = t >> 2;
  const int lgp = (t & 3) * 2;
  const int arow = wi * 32 + (lane & 31);
  const int brow = wj * 32 + (lane & 31);
  const int nc = K >> 6;
#pragma unroll 1
  for (int c = 0; c < nc; ++c) {
    const unsigned short* sa = A + (size_t)(i0 + lrow) * K + c * 64 + lgp * 8;
    const unsigned short* sb = B + (size_t)(j0 + lrow) * K + c * 64 + lgp * 8;
    u16x8 va0 = *(const u16x8*)(sa);
    u16x8 va1 = *(const u16x8*)(sa + 8);
    u16x8 vb0 = *(const u16x8*)(sb);
    u16x8 vb1 = *(const u16x8*)(sb + 8);
    __syncthreads();
    int s0 = (lgp ^ (lrow & 7)) * 8;
    int s1 = ((lgp + 1) ^ (lrow & 7)) * 8;
    *(u16x8*)&Asw[lrow * 64 + s0] = va0;
    *(u16x8*)&Asw[lrow * 64 + s1] = va1;
    *(u16x8*)&Bsw[lrow * 64 + s0] = vb0;
    *(u16x8*)&Bsw[lrow * 64 + s1] = vb1;
    __syncthreads();
#pragma unroll
    for (int s = 0; s < 4; ++s) {
      int slot = s * 2 + khalf;
      bf16x8 a = *(const bf16x8*)&Asw[arow * 64 + ((slot ^ (arow & 7)) * 8)];
      bf16x8 b = *(const bf16x8*)&Bsw[brow * 64 + ((slot ^ (brow & 7)) * 8)];
      acc = __builtin_amdgcn_mfma_f32_32x32x16_bf16(a, b, acc, 0, 0, 0);
    }
  }
#pragma unroll
  for (int r = 0; r < 16; ++r) {
    int rowl = (r & 3) + 8 * (r >> 2) + 4 * khalf;
    int coll = lane & 31;
    C[(size_t)(i0 + wi * 32 + rowl) * NN + j0 + wj * 32 + coll] = acc[r];
  }
}

// per-column partial sums (deterministic two-stage BN stats)
__global__ __launch_bounds__(256) void colstats(const float* __restrict__ in, int C,
                                                float* __restrict__ pS,
                                                float* __restrict__ pSS) {
  const int t = threadIdx.x;
  const int col = blockIdx.x * 64 + (t & 63);
  const int rp = t >> 6;
  const int r0 = blockIdx.y * 128;
  float s = 0.f, ss = 0.f;
  for (int r = rp; r < 128; r += 4) {
    float v = in[(size_t)(r0 + r) * C + col];
    s += v; ss += v * v;
  }
  __shared__ float lS[4][64], lQ[4][64];
  lS[rp][t & 63] = s; lQ[rp][t & 63] = ss;
  __syncthreads();
  if (t < 64) {
    float ts = lS[0][t] + lS[1][t] + lS[2][t] + lS[3][t];
    float tq = lQ[0][t] + lQ[1][t] + lQ[2][t] + lQ[3][t];
    pS[(size_t)blockIdx.y * C + blockIdx.x * 64 + t] = ts;
    pSS[(size_t)blockIdx.y * C + blockIdx.x * 64 + t] = tq;
  }
}

__global__ void bn_finalize(const float* __restrict__ pS, const float* __restrict__ pSS,
                            const float* __restrict__ g, const float* __restrict__ be,
                            float2* __restrict__ ab, int C) {
  int c = blockIdx.x * 256 + threadIdx.x;
  if (c >= C) return;
  float s = 0.f, q = 0.f;
  for (int r = 0; r < 64; ++r) { s += pS[r * C + c]; q += pSS[r * C + c]; }
  const float invM = 1.f / 8192.f;
  float mu = s * invM;
  float var = q * invM - mu * mu;
  float rstd = rsqrtf(var + 1e-5f);
  float a = g[c] * rstd;
  ab[c] = make_float2(a, be[c] - mu * a);
}

// layer-1: hb(bf16) = leaky_relu(a*h + b)  (fp32 h read, bf16 write only)
__global__ __launch_bounds__(256) void bn_act_h2b(const float* __restrict__ h,
                                                  const float2* __restrict__ ab,
                                                  unsigned short* __restrict__ hb,
                                                  int Cmask) {
  size_t idx = (size_t)blockIdx.x * 256 + threadIdx.x;
  float4 v = ((const float4*)h)[idx];
  int cb = (int)((idx * 4) & (size_t)Cmask);
  float2 a0 = ab[cb], a1 = ab[cb + 1], a2 = ab[cb + 2], a3 = ab[cb + 3];
  float r0 = a0.x * v.x + a0.y; r0 = r0 >= 0.f ? r0 : 0.01f * r0;
  float r1 = a1.x * v.y + a1.y; r1 = r1 >= 0.f ? r1 : 0.01f * r1;
  float r2 = a2.x * v.z + a2.y; r2 = r2 >= 0.f ? r2 : 0.01f * r2;
  float r3 = a3.x * v.w + a3.y; r3 = r3 >= 0.f ? r3 : 0.01f * r3;
  *(ushort4*)(hb + idx * 4) = make_ushort4(f2bf(r0), f2bf(r1), f2bf(r2), f2bf(r3));
}

// in-place: h = leaky_relu(a*h + b), per column (fp32)
__global__ __launch_bounds__(256) void bn_act(float* __restrict__ h,
                                              const float2* __restrict__ ab,
                                              int Cmask) {
  size_t idx = (size_t)blockIdx.x * 256 + threadIdx.x;
  float4 v = ((const float4*)h)[idx];
  int cb = (int)((idx * 4) & (size_t)Cmask);
  float2 a0 = ab[cb], a1 = ab[cb + 1], a2 = ab[cb + 2], a3 = ab[cb + 3];
  float r0 = a0.x * v.x + a0.y; r0 = r0 >= 0.f ? r0 : 0.01f * r0;
  float r1 = a1.x * v.y + a1.y; r1 = r1 >= 0.f ? r1 : 0.01f * r1;
  float r2 = a2.x * v.z + a2.y; r2 = r2 >= 0.f ? r2 : 0.01f * r2;
  float r3 = a3.x * v.w + a3.y; r3 = r3 >= 0.f ? r3 : 0.01f * r3;
  ((float4*)h)[idx] = make_float4(r0, r1, r2, r3);
}

// per row: fn, unary logit, coef0; write row-normalized feats as bf16
__global__ __launch_bounds__(256) void rowfn(const float* __restrict__ feats,
                                             const float* __restrict__ fcw,
                                             const float* __restrict__ fcb,
                                             unsigned short* __restrict__ fnorm,
                                             float* __restrict__ unary,
                                             float* __restrict__ coef0) {
  const int lane = threadIdx.x & 63;
  const int row = blockIdx.x * 4 + (threadIdx.x >> 6);
  const float* fr = feats + (size_t)row * 256;
  float4 v = *(const float4*)(fr + lane * 4);
  float4 w = *(const float4*)(fcw + lane * 4);
  float ssq = v.x * v.x + v.y * v.y + v.z * v.z + v.w * v.w;
  float dot = v.x * w.x + v.y * w.y + v.z * w.z + v.w * w.w;
#pragma unroll
  for (int o = 32; o; o >>= 1) { ssq += __shfl_xor(ssq, o); dot += __shfl_xor(dot, o); }
  float rfn = rsqrtf(ssq);
  *(ushort4*)(fnorm + (size_t)row * 256 + lane * 4) =
      make_ushort4(f2bf(v.x * rfn), f2bf(v.y * rfn), f2bf(v.z * rfn), f2bf(v.w * rfn));
  if (lane == 0) {
    float lg = dot + fcb[0];
    unary[row] = lg;
    coef0[row] = 1.f - 2.f / (1.f + __expf(-lg));
  }
}

// PP[i,j] = (fnorm_i . fnorm_j) * 0.5*(W[i,j]+W[j,i])  stored bf16
// Triangular grid; LDS time-multiplexed phase1 Asw/Bsw -> phase2 Wt ->
// phase3 OutD/OutT.
__global__ __launch_bounds__(256) void ppbuild_sym(const unsigned short* __restrict__ fnorm,
                                                   const float* __restrict__ W,
                                                   unsigned short* __restrict__ PP) {
#define TRIS(b) ((b) * (257 - (b)) / 2)
  const int L = blockIdx.x;
  int bi = (int)((257.0f - sqrtf((float)(66049 - 8 * L))) * 0.5f);
  if (bi > 127) bi = 127;
  if (bi < 0) bi = 0;
  while (bi < 127 && TRIS(bi + 1) <= L) ++bi;
  while (bi > 0 && TRIS(bi) > L) --bi;
  const int bj = bi + (L - TRIS(bi));
  const int i0 = bi * 64, j0 = bj * 64;

  __shared__ __align__(16) unsigned char shm[18944];
  unsigned short* Asw = (unsigned short*)shm;
  unsigned short* Bsw = (unsigned short*)shm + 4736;
  float (*Wt)[68] = (float(*)[68])shm;
  unsigned short* OutD = (unsigned short*)shm;
  unsigned short* OutT = (unsigned short*)shm + 4736;

  const int t = threadIdx.x;
  const int lane = t & 63;
  const int wv = t >> 6;
  const int wi = wv >> 1, wj = wv & 1;
  const int khalf = lane >> 5;

  f32x16 acc;
#pragma unroll
  for (int r = 0; r < 16; ++r) acc[r] = 0.f;

  const int lrow = t >> 2;
  const int lgp = (t & 3) * 2;
  const int arow = wi * 32 + (lane & 31);
  const int brow = wj * 32 + (lane & 31);
#pragma unroll 1
  for (int c = 0; c < 4; ++c) {
    const unsigned short* sa = fnorm + (size_t)(i0 + lrow) * 256 + c * 64 + lgp * 8;
    const unsigned short* sb = fnorm + (size_t)(j0 + lrow) * 256 + c * 64 + lgp * 8;
    u16x8 va0 = *(const u16x8*)(sa);
    u16x8 va1 = *(const u16x8*)(sa + 8);
    u16x8 vb0 = *(const u16x8*)(sb);
    u16x8 vb1 = *(const u16x8*)(sb + 8);
    __syncthreads();
    int s0 = (lgp ^ (lrow & 7)) * 8;
    int s1 = ((lgp + 1) ^ (lrow & 7)) * 8;
    *(u16x8*)&Asw[lrow * 64 + s0] = va0;
    *(u16x8*)&Asw[lrow * 64 + s1] = va1;
    *(u16x8*)&Bsw[lrow * 64 + s0] = vb0;
    *(u16x8*)&Bsw[lrow * 64 + s1] = vb1;
    __syncthreads();
#pragma unroll
    for (int s = 0; s < 4; ++s) {
      int slot = s * 2 + khalf;
      bf16x8 a = *(const bf16x8*)&Asw[arow * 64 + ((slot ^ (arow & 7)) * 8)];
      bf16x8 b = *(const bf16x8*)&Bsw[brow * 64 + ((slot ^ (brow & 7)) * 8)];
      acc = __builtin_amdgcn_mfma_f32_32x32x16_bf16(a, b, acc, 0, 0, 0);
    }
  }

  __syncthreads();
  {
    const int j = t >> 2, cb = (t & 3) * 16;
    const float* src = W + (size_t)(j0 + j) * NROWS + i0 + cb;
#pragma unroll
    for (int q = 0; q < 4; ++q) {
      float4 v = *(const float4*)(src + q * 4);
      Wt[j][cb + q * 4 + 0] = v.x; Wt[j][cb + q * 4 + 1] = v.y;
      Wt[j][cb + q * 4 + 2] = v.z; Wt[j][cb + q * 4 + 3] = v.w;
    }
  }
  __syncthreads();
  unsigned short pb[16];
#pragma unroll
  for (int r = 0; r < 16; ++r) {
    int rowl = (r & 3) + 8 * (r >> 2) + 4 * khalf;
    int coll = lane & 31;
    int il = wi * 32 + rowl, jl = wj * 32 + coll;
    float wd = W[(size_t)(i0 + il) * NROWS + (j0 + jl)];
    float ws = 0.5f * (wd + Wt[jl][il]);
    pb[r] = f2bf(acc[r] * ws);
  }
  __syncthreads();
#pragma unroll
  for (int r = 0; r < 16; ++r) {
    int rowl = (r & 3) + 8 * (r >> 2) + 4 * khalf;
    int coll = lane & 31;
    int il = wi * 32 + rowl, jl = wj * 32 + coll;
    OutD[il * 74 + jl] = pb[r];
    OutT[jl * 74 + il] = pb[r];
  }
  __syncthreads();
  const int row = t >> 3;
  const int seg = t & 7;
#pragma unroll
  for (int q = 0; q < 2; ++q) {
    int rr = row + q * 32;
    const unsigned int* pd = (const unsigned int*)(OutD + rr * 74 + seg * 8);
    const unsigned int* pt = (const unsigned int*)(OutT + rr * 74 + seg * 8);
    union { u16x8 v; unsigned int u[4]; } dd, tt;
#pragma unroll
    for (int k = 0; k < 4; ++k) { dd.u[k] = pd[k]; tt.u[k] = pt[k]; }
    *(u16x8*)(PP + (size_t)(i0 + rr) * NROWS + j0 + seg * 8) = dd.v;
    *(u16x8*)(PP + (size_t)(j0 + rr) * NROWS + i0 + seg * 8) = tt.v;
  }
#undef TRIS
}

// one row of E = PP @ coef; lg = unary + E; coef_out = 1-2*sigmoid(lg)
__global__ __launch_bounds__(256) void ppmv(const unsigned short* __restrict__ PP,
                                            const float* __restrict__ coef_in,
                                            const float* __restrict__ unary,
                                            float* __restrict__ coef_out,
                                            float* __restrict__ lg_out) {
  const int i = blockIdx.x;
  const unsigned short* row = PP + (size_t)i * NROWS;
  float acc = 0.f;
#pragma unroll
  for (int cc = 0; cc < 4; ++cc) {
    int j0 = (cc * 256 + threadIdx.x) * 8;
    u16x8 p = *(const u16x8*)(row + j0);
    float4 c0 = *(const float4*)(coef_in + j0);
    float4 c1 = *(const float4*)(coef_in + j0 + 4);
    acc += bf2f(p[0]) * c0.x + bf2f(p[1]) * c0.y + bf2f(p[2]) * c0.z + bf2f(p[3]) * c0.w;
    acc += bf2f(p[4]) * c1.x + bf2f(p[5]) * c1.y + bf2f(p[6]) * c1.z + bf2f(p[7]) * c1.w;
  }
#pragma unroll
  for (int o = 32; o; o >>= 1) acc += __shfl_xor(acc, o);
  __shared__ float red[4];
  if ((threadIdx.x & 63) == 0) red[threadIdx.x >> 6] = acc;
  __syncthreads();
  if (threadIdx.x == 0) {
    float tot = red[0] + red[1] + red[2] + red[3];
    float lg = unary[i] + tot;
    coef_out[i] = 1.f - 2.f / (1.f + __expf(-lg));
    if (lg_out) lg_out[i] = lg;
  }
}

extern "C" void kernel_launch(void* const* d_in, const int* in_sizes, int n_in,
                              void* d_out, int out_size, void* d_ws, size_t ws_size,
                              hipStream_t stream) {
  const float* x   = (const float*)d_in[0];
  const float* W   = (const float*)d_in[1];
  const float* W1  = (const float*)d_in[2];
  const float* g1  = (const float*)d_in[4];
  const float* be1 = (const float*)d_in[5];
  const float* W2  = (const float*)d_in[6];
  const float* g2  = (const float*)d_in[8];
  const float* be2 = (const float*)d_in[9];
  const float* fcw = (const float*)d_in[10];
  const float* fcb = (const float*)d_in[11];
  float* out = (float*)d_out;

  char* ws = (char*)d_ws;
  float* h      = (float*)(ws + 0);              // 8192*512*4  = 16 MB
  float* feats  = (float*)(ws + 16777216);       // 8192*256*4  = 8 MB
  float* p1s    = (float*)(ws + 25165824);
  float* p1q    = (float*)(ws + 25296896);
  float* p2s    = (float*)(ws + 25427968);
  float* p2q    = (float*)(ws + 25493504);
  float2* ab1   = (float2*)(ws + 25559040);
  float2* ab2   = (float2*)(ws + 25563136);
  unsigned short* fnorm = (unsigned short*)(ws + 25565184);  // 4 MB
  float* unary  = (float*)(ws + 29759488);
  float* coefA  = (float*)(ws + 29792256);
  float* coefB  = (float*)(ws + 29825024);
  unsigned short* PP  = (unsigned short*)(ws + 29857792);    // 128 MB
  unsigned short* xb  = (unsigned short*)(ws + 164075520);   // 8192*128*2 = 2 MB
  unsigned short* w1b = (unsigned short*)(ws + 166172672);   // 512*128*2
  unsigned short* w2b = (unsigned short*)(ws + 166303744);   // 256*512*2
  unsigned short* hb  = (unsigned short*)(ws + 166565888);   // 8192*512*2 = 8 MB
  if (ws_size < (size_t)174954496) return;

  // bf16 casts of MLP inputs/weights
  cast_bf16<<<512, 256, 0, stream>>>(x, xb, 131072);     // 8192*128/8
  cast_bf16<<<32, 256, 0, stream>>>(W1, w1b, 8192);      // 512*128/8
  cast_bf16<<<64, 256, 0, stream>>>(W2, w2b, 16384);     // 256*512/8
  // layer 1: h = x @ W1^T (MFMA) ; BN ; leaky -> hb (bf16)
  gemm_bt_mfma<<<dim3(128, 8), 256, 0, stream>>>(xb, w1b, h, 512, 128);
  colstats<<<dim3(8, 64), 256, 0, stream>>>(h, 512, p1s, p1q);
  bn_finalize<<<2, 256, 0, stream>>>(p1s, p1q, g1, be1, ab1, 512);
  bn_act_h2b<<<4096, 256, 0, stream>>>(h, ab1, hb, 511);
  // layer 2: feats = hb @ W2^T (MFMA) ; BN ; leaky (fp32 in place)
  gemm_bt_mfma<<<dim3(128, 4), 256, 0, stream>>>(hb, w2b, feats, 256, 512);
  colstats<<<dim3(4, 64), 256, 0, stream>>>(feats, 256, p2s, p2q);
  bn_finalize<<<1, 256, 0, stream>>>(p2s, p2q, g2, be2, ab2, 256);
  bn_act<<<2048, 256, 0, stream>>>(feats, ab2, 255);
  // row norms + unary logits + coef0
  rowfn<<<2048, 256, 0, stream>>>(feats, fcw, fcb, fnorm, unary, coefA);
  // PP = sim * W_sym  (bf16), triangular tile grid
  ppbuild_sym<<<8256, 256, 0, stream>>>(fnorm, W, PP);
  // 10 sequential matvec iterations
  float* cur = coefA; float* nxt = coefB;
  for (int it = 0; it < NITER; ++it) {
    ppmv<<<8192, 256, 0, stream>>>(PP, cur, unary, nxt, it == NITER - 1 ? out : nullptr);
    float* tmp = cur; cur = nxt; nxt = tmp;
  }
}

// Round 8
// 358.375 us; speedup vs baseline: 1.6380x; 1.0558x over previous
//
#include <hip/hip_runtime.h>
#include <hip/hip_bf16.h>

#define NROWS 8192
#define NITER 10

typedef __attribute__((ext_vector_type(8))) short bf16x8;
typedef __attribute__((ext_vector_type(8))) unsigned short u16x8;
typedef __attribute__((ext_vector_type(16))) float f32x16;

__device__ __forceinline__ float bf2f(unsigned short u) {
  union { float f; unsigned int i; } c; c.i = ((unsigned int)u) << 16; return c.f;
}
__device__ __forceinline__ unsigned short f2bf(float f) {
  unsigned int x = __float_as_uint(f);
  unsigned int r = (x + 0x7FFFu + ((x >> 16) & 1u)) >> 16;
  return (unsigned short)r;
}

// tril inversion shared by the triangular-grid kernels
#define TRIS(b) ((b) * (257 - (b)) / 2)
__device__ __forceinline__ void tril_decode(int L, int& bi, int& bj) {
  int b = (int)((257.0f - sqrtf((float)(66049 - 8 * L))) * 0.5f);
  if (b > 127) b = 127;
  if (b < 0) b = 0;
  while (b < 127 && TRIS(b + 1) <= L) ++b;
  while (b > 0 && TRIS(b) > L) --b;
  bi = b;
  bj = b + (L - TRIS(b));
}

// fp32 -> bf16 cast, 8 elems/thread
__global__ __launch_bounds__(256) void cast_bf16(const float* __restrict__ in,
                                                 unsigned short* __restrict__ out,
                                                 int n8) {
  int idx = blockIdx.x * 256 + threadIdx.x;
  if (idx >= n8) return;
  const float4* p = (const float4*)in + (size_t)idx * 2;
  float4 a = p[0], b = p[1];
  u16x8 o;
  o[0] = f2bf(a.x); o[1] = f2bf(a.y); o[2] = f2bf(a.z); o[3] = f2bf(a.w);
  o[4] = f2bf(b.x); o[5] = f2bf(b.y); o[6] = f2bf(b.z); o[7] = f2bf(b.w);
  *(u16x8*)(out + (size_t)idx * 8) = o;
}

// C[M,NN] = A[M,K] @ B[NN,K]^T, bf16 inputs, fp32 out. 64x64 tile, 4 waves.
__global__ __launch_bounds__(256) void gemm_bt_mfma(const unsigned short* __restrict__ A,
                                                    const unsigned short* __restrict__ B,
                                                    float* __restrict__ C,
                                                    int NN, int K) {
  __shared__ __align__(16) unsigned short Asw[4096];
  __shared__ __align__(16) unsigned short Bsw[4096];
  const int i0 = blockIdx.x * 64, j0 = blockIdx.y * 64;
  const int t = threadIdx.x;
  const int lane = t & 63;
  const int wv = t >> 6;
  const int wi = wv >> 1, wj = wv & 1;
  const int khalf = lane >> 5;

  f32x16 acc;
#pragma unroll
  for (int r = 0; r < 16; ++r) acc[r] = 0.f;

  const int lrow = t >> 2;
  const int lgp = (t & 3) * 2;
  const int arow = wi * 32 + (lane & 31);
  const int brow = wj * 32 + (lane & 31);
  const int nc = K >> 6;
#pragma unroll 1
  for (int c = 0; c < nc; ++c) {
    const unsigned short* sa = A + (size_t)(i0 + lrow) * K + c * 64 + lgp * 8;
    const unsigned short* sb = B + (size_t)(j0 + lrow) * K + c * 64 + lgp * 8;
    u16x8 va0 = *(const u16x8*)(sa);
    u16x8 va1 = *(const u16x8*)(sa + 8);
    u16x8 vb0 = *(const u16x8*)(sb);
    u16x8 vb1 = *(const u16x8*)(sb + 8);
    __syncthreads();
    int s0 = (lgp ^ (lrow & 7)) * 8;
    int s1 = ((lgp + 1) ^ (lrow & 7)) * 8;
    *(u16x8*)&Asw[lrow * 64 + s0] = va0;
    *(u16x8*)&Asw[lrow * 64 + s1] = va1;
    *(u16x8*)&Bsw[lrow * 64 + s0] = vb0;
    *(u16x8*)&Bsw[lrow * 64 + s1] = vb1;
    __syncthreads();
#pragma unroll
    for (int s = 0; s < 4; ++s) {
      int slot = s * 2 + khalf;
      bf16x8 a = *(const bf16x8*)&Asw[arow * 64 + ((slot ^ (arow & 7)) * 8)];
      bf16x8 b = *(const bf16x8*)&Bsw[brow * 64 + ((slot ^ (brow & 7)) * 8)];
      acc = __builtin_amdgcn_mfma_f32_32x32x16_bf16(a, b, acc, 0, 0, 0);
    }
  }
#pragma unroll
  for (int r = 0; r < 16; ++r) {
    int rowl = (r & 3) + 8 * (r >> 2) + 4 * khalf;
    int coll = lane & 31;
    C[(size_t)(i0 + wi * 32 + rowl) * NN + j0 + wj * 32 + coll] = acc[r];
  }
}

// per-column partial sums (deterministic two-stage BN stats)
__global__ __launch_bounds__(256) void colstats(const float* __restrict__ in, int C,
                                                float* __restrict__ pS,
                                                float* __restrict__ pSS) {
  const int t = threadIdx.x;
  const int col = blockIdx.x * 64 + (t & 63);
  const int rp = t >> 6;
  const int r0 = blockIdx.y * 128;
  float s = 0.f, ss = 0.f;
  for (int r = rp; r < 128; r += 4) {
    float v = in[(size_t)(r0 + r) * C + col];
    s += v; ss += v * v;
  }
  __shared__ float lS[4][64], lQ[4][64];
  lS[rp][t & 63] = s; lQ[rp][t & 63] = ss;
  __syncthreads();
  if (t < 64) {
    float ts = lS[0][t] + lS[1][t] + lS[2][t] + lS[3][t];
    float tq = lQ[0][t] + lQ[1][t] + lQ[2][t] + lQ[3][t];
    pS[(size_t)blockIdx.y * C + blockIdx.x * 64 + t] = ts;
    pSS[(size_t)blockIdx.y * C + blockIdx.x * 64 + t] = tq;
  }
}

__global__ void bn_finalize(const float* __restrict__ pS, const float* __restrict__ pSS,
                            const float* __restrict__ g, const float* __restrict__ be,
                            float2* __restrict__ ab, int C) {
  int c = blockIdx.x * 256 + threadIdx.x;
  if (c >= C) return;
  float s = 0.f, q = 0.f;
  for (int r = 0; r < 64; ++r) { s += pS[r * C + c]; q += pSS[r * C + c]; }
  const float invM = 1.f / 8192.f;
  float mu = s * invM;
  float var = q * invM - mu * mu;
  float rstd = rsqrtf(var + 1e-5f);
  float a = g[c] * rstd;
  ab[c] = make_float2(a, be[c] - mu * a);
}

// layer-1: hb(bf16) = leaky_relu(a*h + b)
__global__ __launch_bounds__(256) void bn_act_h2b(const float* __restrict__ h,
                                                  const float2* __restrict__ ab,
                                                  unsigned short* __restrict__ hb,
                                                  int Cmask) {
  size_t idx = (size_t)blockIdx.x * 256 + threadIdx.x;
  float4 v = ((const float4*)h)[idx];
  int cb = (int)((idx * 4) & (size_t)Cmask);
  float2 a0 = ab[cb], a1 = ab[cb + 1], a2 = ab[cb + 2], a3 = ab[cb + 3];
  float r0 = a0.x * v.x + a0.y; r0 = r0 >= 0.f ? r0 : 0.01f * r0;
  float r1 = a1.x * v.y + a1.y; r1 = r1 >= 0.f ? r1 : 0.01f * r1;
  float r2 = a2.x * v.z + a2.y; r2 = r2 >= 0.f ? r2 : 0.01f * r2;
  float r3 = a3.x * v.w + a3.y; r3 = r3 >= 0.f ? r3 : 0.01f * r3;
  *(ushort4*)(hb + idx * 4) = make_ushort4(f2bf(r0), f2bf(r1), f2bf(r2), f2bf(r3));
}

// in-place: h = leaky_relu(a*h + b), per column (fp32)
__global__ __launch_bounds__(256) void bn_act(float* __restrict__ h,
                                              const float2* __restrict__ ab,
                                              int Cmask) {
  size_t idx = (size_t)blockIdx.x * 256 + threadIdx.x;
  float4 v = ((const float4*)h)[idx];
  int cb = (int)((idx * 4) & (size_t)Cmask);
  float2 a0 = ab[cb], a1 = ab[cb + 1], a2 = ab[cb + 2], a3 = ab[cb + 3];
  float r0 = a0.x * v.x + a0.y; r0 = r0 >= 0.f ? r0 : 0.01f * r0;
  float r1 = a1.x * v.y + a1.y; r1 = r1 >= 0.f ? r1 : 0.01f * r1;
  float r2 = a2.x * v.z + a2.y; r2 = r2 >= 0.f ? r2 : 0.01f * r2;
  float r3 = a3.x * v.w + a3.y; r3 = r3 >= 0.f ? r3 : 0.01f * r3;
  ((float4*)h)[idx] = make_float4(r0, r1, r2, r3);
}

// per row: fn, unary logit, coef0; write row-normalized feats as bf16
__global__ __launch_bounds__(256) void rowfn(const float* __restrict__ feats,
                                             const float* __restrict__ fcw,
                                             const float* __restrict__ fcb,
                                             unsigned short* __restrict__ fnorm,
                                             float* __restrict__ unary,
                                             float* __restrict__ coef0) {
  const int lane = threadIdx.x & 63;
  const int row = blockIdx.x * 4 + (threadIdx.x >> 6);
  const float* fr = feats + (size_t)row * 256;
  float4 v = *(const float4*)(fr + lane * 4);
  float4 w = *(const float4*)(fcw + lane * 4);
  float ssq = v.x * v.x + v.y * v.y + v.z * v.z + v.w * v.w;
  float dot = v.x * w.x + v.y * w.y + v.z * w.z + v.w * w.w;
#pragma unroll
  for (int o = 32; o; o >>= 1) { ssq += __shfl_xor(ssq, o); dot += __shfl_xor(dot, o); }
  float rfn = rsqrtf(ssq);
  *(ushort4*)(fnorm + (size_t)row * 256 + lane * 4) =
      make_ushort4(f2bf(v.x * rfn), f2bf(v.y * rfn), f2bf(v.z * rfn), f2bf(v.w * rfn));
  if (lane == 0) {
    float lg = dot + fcb[0];
    unary[row] = lg;
    coef0[row] = 1.f - 2.f / (1.f + __expf(-lg));
  }
}

// PP[i,j] = (fnorm_i . fnorm_j) * 0.5*(W[i,j]+W[j,i])  stored bf16
// Triangular grid; ONLY the upper-triangle tile is written (no mirror).
__global__ __launch_bounds__(256) void ppbuild_sym(const unsigned short* __restrict__ fnorm,
                                                   const float* __restrict__ W,
                                                   unsigned short* __restrict__ PP) {
  int bi, bj;
  tril_decode(blockIdx.x, bi, bj);
  const int i0 = bi * 64, j0 = bj * 64;

  __shared__ __align__(16) unsigned char shm[18944];
  unsigned short* Asw = (unsigned short*)shm;
  unsigned short* Bsw = (unsigned short*)shm + 4736;
  float (*Wt)[68] = (float(*)[68])shm;
  unsigned short* OutD = (unsigned short*)shm;

  const int t = threadIdx.x;
  const int lane = t & 63;
  const int wv = t >> 6;
  const int wi = wv >> 1, wj = wv & 1;
  const int khalf = lane >> 5;

  f32x16 acc;
#pragma unroll
  for (int r = 0; r < 16; ++r) acc[r] = 0.f;

  const int lrow = t >> 2;
  const int lgp = (t & 3) * 2;
  const int arow = wi * 32 + (lane & 31);
  const int brow = wj * 32 + (lane & 31);
#pragma unroll 1
  for (int c = 0; c < 4; ++c) {
    const unsigned short* sa = fnorm + (size_t)(i0 + lrow) * 256 + c * 64 + lgp * 8;
    const unsigned short* sb = fnorm + (size_t)(j0 + lrow) * 256 + c * 64 + lgp * 8;
    u16x8 va0 = *(const u16x8*)(sa);
    u16x8 va1 = *(const u16x8*)(sa + 8);
    u16x8 vb0 = *(const u16x8*)(sb);
    u16x8 vb1 = *(const u16x8*)(sb + 8);
    __syncthreads();
    int s0 = (lgp ^ (lrow & 7)) * 8;
    int s1 = ((lgp + 1) ^ (lrow & 7)) * 8;
    *(u16x8*)&Asw[lrow * 64 + s0] = va0;
    *(u16x8*)&Asw[lrow * 64 + s1] = va1;
    *(u16x8*)&Bsw[lrow * 64 + s0] = vb0;
    *(u16x8*)&Bsw[lrow * 64 + s1] = vb1;
    __syncthreads();
#pragma unroll
    for (int s = 0; s < 4; ++s) {
      int slot = s * 2 + khalf;
      bf16x8 a = *(const bf16x8*)&Asw[arow * 64 + ((slot ^ (arow & 7)) * 8)];
      bf16x8 b = *(const bf16x8*)&Bsw[brow * 64 + ((slot ^ (brow & 7)) * 8)];
      acc = __builtin_amdgcn_mfma_f32_32x32x16_bf16(a, b, acc, 0, 0, 0);
    }
  }

  __syncthreads();
  {
    const int j = t >> 2, cb = (t & 3) * 16;
    const float* src = W + (size_t)(j0 + j) * NROWS + i0 + cb;
#pragma unroll
    for (int q = 0; q < 4; ++q) {
      float4 v = *(const float4*)(src + q * 4);
      Wt[j][cb + q * 4 + 0] = v.x; Wt[j][cb + q * 4 + 1] = v.y;
      Wt[j][cb + q * 4 + 2] = v.z; Wt[j][cb + q * 4 + 3] = v.w;
    }
  }
  __syncthreads();
  unsigned short pb[16];
#pragma unroll
  for (int r = 0; r < 16; ++r) {
    int rowl = (r & 3) + 8 * (r >> 2) + 4 * khalf;
    int coll = lane & 31;
    int il = wi * 32 + rowl, jl = wj * 32 + coll;
    float wd = W[(size_t)(i0 + il) * NROWS + (j0 + jl)];
    float ws = 0.5f * (wd + Wt[jl][il]);
    pb[r] = f2bf(acc[r] * ws);
  }
  __syncthreads();
#pragma unroll
  for (int r = 0; r < 16; ++r) {
    int rowl = (r & 3) + 8 * (r >> 2) + 4 * khalf;
    int coll = lane & 31;
    OutD[(wi * 32 + rowl) * 74 + wj * 32 + coll] = pb[r];
  }
  __syncthreads();
  const int row = t >> 3;
  const int seg = t & 7;
#pragma unroll
  for (int q = 0; q < 2; ++q) {
    int rr = row + q * 32;
    const unsigned int* pd = (const unsigned int*)(OutD + rr * 74 + seg * 8);
    union { u16x8 v; unsigned int u[4]; } dd;
#pragma unroll
    for (int k = 0; k < 4; ++k) dd.u[k] = pd[k];
    *(u16x8*)(PP + (size_t)(i0 + rr) * NROWS + j0 + seg * 8) = dd.v;
  }
}

// Symmetric matvec partials over upper-triangle tiles.
// Tile (bi,bj): D[r] = sum_c PP[r][c]*coef[j0+c]  -> pE[bj][i0+r]
//              T[c] = sum_r PP[r][c]*coef[i0+r]  -> pE[bi][j0+c]  (bi!=bj)
// Every pE cell is written exactly once per iteration (deterministic).
__global__ __launch_bounds__(256) void ppmv_sym(const unsigned short* __restrict__ PP,
                                                const float* __restrict__ coef_in,
                                                float* __restrict__ pE) {
  int bi, bj;
  tril_decode(blockIdx.x, bi, bj);
  const int i0 = bi * 64, j0 = bj * 64;
  const int t = threadIdx.x;

  __shared__ unsigned short tile[64][68];
  __shared__ float cj[64], ci[64], Tw[4][64], Dred[64];
  if (t < 64) cj[t] = coef_in[j0 + t];
  else if (t < 128) ci[t - 64] = coef_in[i0 + (t - 64)];
  {
    int r = t >> 2, c0 = (t & 3) * 16;
    const unsigned short* src = PP + (size_t)(i0 + r) * NROWS + j0 + c0;
    u16x8 v0 = *(const u16x8*)(src);
    u16x8 v1 = *(const u16x8*)(src + 8);
    *(u16x8*)&tile[r][c0] = v0;
    *(u16x8*)&tile[r][c0 + 8] = v1;
  }
  __syncthreads();
  // direct row sums (4 lanes per row)
  {
    int r = t >> 2, c0 = (t & 3) * 16;
    float a = 0.f;
#pragma unroll
    for (int k = 0; k < 16; ++k) a += bf2f(tile[r][c0 + k]) * cj[c0 + k];
    a += __shfl_xor(a, 1);
    a += __shfl_xor(a, 2);
    if ((t & 3) == 0) Dred[r] = a;
  }
  // transposed column sums (per-wave row stripe, no cross-lane)
  {
    int c = t & 63, w = t >> 6;
    float a = 0.f;
#pragma unroll
    for (int k = 0; k < 16; ++k) a += bf2f(tile[w * 16 + k][c]) * ci[w * 16 + k];
    Tw[w][c] = a;
  }
  __syncthreads();
  if (t < 64) {
    pE[(size_t)bj * NROWS + i0 + t] = Dred[t];
    if (bi != bj) {
      float s = (Tw[0][t] + Tw[1][t]) + (Tw[2][t] + Tw[3][t]);
      pE[(size_t)bi * NROWS + j0 + t] = s;
    }
  }
}

// fold 128 slot-partials + unary -> lg; coef_out = 1-2*sigmoid(lg)
__global__ __launch_bounds__(256) void ppmv_reduce(const float* __restrict__ pE,
                                                   const float* __restrict__ unary,
                                                   float* __restrict__ coef_out,
                                                   float* __restrict__ lg_out) {
  int row = blockIdx.x * 256 + threadIdx.x;
  float acc = 0.f;
#pragma unroll 8
  for (int s = 0; s < 128; ++s) acc += pE[(size_t)s * NROWS + row];
  float lg = unary[row] + acc;
  coef_out[row] = 1.f - 2.f / (1.f + __expf(-lg));
  if (lg_out) lg_out[row] = lg;
}

extern "C" void kernel_launch(void* const* d_in, const int* in_sizes, int n_in,
                              void* d_out, int out_size, void* d_ws, size_t ws_size,
                              hipStream_t stream) {
  const float* x   = (const float*)d_in[0];
  const float* W   = (const float*)d_in[1];
  const float* W1  = (const float*)d_in[2];
  const float* g1  = (const float*)d_in[4];
  const float* be1 = (const float*)d_in[5];
  const float* W2  = (const float*)d_in[6];
  const float* g2  = (const float*)d_in[8];
  const float* be2 = (const float*)d_in[9];
  const float* fcw = (const float*)d_in[10];
  const float* fcb = (const float*)d_in[11];
  float* out = (float*)d_out;

  char* ws = (char*)d_ws;
  float* h      = (float*)(ws + 0);              // 16 MB (reused as pE later)
  float* pE     = h;                             // [128][8192] fp32 = 4 MB
  float* feats  = (float*)(ws + 16777216);       // 8 MB
  float* p1s    = (float*)(ws + 25165824);
  float* p1q    = (float*)(ws + 25296896);
  float* p2s    = (float*)(ws + 25427968);
  float* p2q    = (float*)(ws + 25493504);
  float2* ab1   = (float2*)(ws + 25559040);
  float2* ab2   = (float2*)(ws + 25563136);
  unsigned short* fnorm = (unsigned short*)(ws + 25565184);  // 4 MB
  float* unary  = (float*)(ws + 29759488);
  float* coefA  = (float*)(ws + 29792256);
  float* coefB  = (float*)(ws + 29825024);
  unsigned short* PP  = (unsigned short*)(ws + 29857792);    // 128 MB
  unsigned short* xb  = (unsigned short*)(ws + 164075520);   // 2 MB
  unsigned short* w1b = (unsigned short*)(ws + 166172672);
  unsigned short* w2b = (unsigned short*)(ws + 166303744);
  unsigned short* hb  = (unsigned short*)(ws + 166565888);   // 8 MB
  if (ws_size < (size_t)174954496) return;

  // bf16 casts of MLP inputs/weights
  cast_bf16<<<512, 256, 0, stream>>>(x, xb, 131072);
  cast_bf16<<<32, 256, 0, stream>>>(W1, w1b, 8192);
  cast_bf16<<<64, 256, 0, stream>>>(W2, w2b, 16384);
  // layer 1: h = x @ W1^T (MFMA) ; BN ; leaky -> hb (bf16)
  gemm_bt_mfma<<<dim3(128, 8), 256, 0, stream>>>(xb, w1b, h, 512, 128);
  colstats<<<dim3(8, 64), 256, 0, stream>>>(h, 512, p1s, p1q);
  bn_finalize<<<2, 256, 0, stream>>>(p1s, p1q, g1, be1, ab1, 512);
  bn_act_h2b<<<4096, 256, 0, stream>>>(h, ab1, hb, 511);
  // layer 2: feats = hb @ W2^T (MFMA) ; BN ; leaky
  gemm_bt_mfma<<<dim3(128, 4), 256, 0, stream>>>(hb, w2b, feats, 256, 512);
  colstats<<<dim3(4, 64), 256, 0, stream>>>(feats, 256, p2s, p2q);
  bn_finalize<<<1, 256, 0, stream>>>(p2s, p2q, g2, be2, ab2, 256);
  bn_act<<<2048, 256, 0, stream>>>(feats, ab2, 255);
  // row norms + unary logits + coef0
  rowfn<<<2048, 256, 0, stream>>>(feats, fcw, fcb, fnorm, unary, coefA);
  // PP upper triangle (h is dead from here; pE aliases it)
  ppbuild_sym<<<8256, 256, 0, stream>>>(fnorm, W, PP);
  // 10 sequential symmetric-matvec iterations
  float* cur = coefA; float* nxt = coefB;
  for (int it = 0; it < NITER; ++it) {
    ppmv_sym<<<8256, 256, 0, stream>>>(PP, cur, pE);
    ppmv_reduce<<<32, 256, 0, stream>>>(pE, unary, nxt, it == NITER - 1 ? out : nullptr);
    float* tmp = cur; cur = nxt; nxt = tmp;
  }
}